// Round 9
// baseline (335.121 us; speedup 1.0000x reference)
//
#include <hip/hip_runtime.h>
#include <hip/hip_fp16.h>

#define RANK 12
#define RES 192
#define NHW (RES * RES)
#define NF 36
#define ODIM 32
#define TEXW 16            // halfs per texel (12 used + 4 pad) -> 32 B
#define NB 4096            // 16^3 cells, 4 bits/dim
#define SORTB 256          // sort blocks
#define SORTT 1024         // threads per sort block
#define REG 14             // texel span of one cell's tap region
#define REGP 16            // padded row stride (texels)

typedef float f32x4 __attribute__((ext_vector_type(4)));
typedef _Float16 h2 __attribute__((ext_vector_type(2)));

__device__ __forceinline__ float fdot2(h2 a, h2 b, float c) {
#if __has_builtin(__builtin_amdgcn_fdot2)
    return __builtin_amdgcn_fdot2(a, b, c, false);
#else
    return c + (float)a.x * (float)b.x + (float)a.y * (float)b.y;
#endif
}

// ---------------------------------------------------------------------------
// Pre-pass: planes [R][H][W] f32 -> [3][H][W][16] fp16 (3.54 MB, L2-resident)
// + pack w_mlp into half2 words (576 u32) when w2u != nullptr
// ---------------------------------------------------------------------------
__global__ __launch_bounds__(256) void vme_transpose(const float* __restrict__ a,
                                                     const float* __restrict__ b,
                                                     const float* __restrict__ c,
                                                     const float* __restrict__ w,
                                                     _Float16* __restrict__ t,
                                                     unsigned* __restrict__ w2u) {
    int idx = blockIdx.x * 256 + threadIdx.x;
    if (w2u != nullptr && idx < ODIM * NF / 2) {   // 576 packed weight words
        int o = idx / (NF / 2), k = idx - o * (NF / 2);
        union { h2 h; unsigned u; } cv;
        cv.h.x = (_Float16)w[o * NF + 2 * k];
        cv.h.y = (_Float16)w[o * NF + 2 * k + 1];
        w2u[idx] = cv.u;
    }
    if (idx >= 3 * NHW) return;
    int p = idx / NHW;
    int yx = idx - p * NHW;
    const float* src = (p == 0) ? a : (p == 1) ? b : c;
    _Float16* dst = t + (size_t)idx * TEXW;
#pragma unroll
    for (int r = 0; r < RANK; ++r) dst[r] = (_Float16)src[(size_t)r * NHW + yx];
#pragma unroll
    for (int r = RANK; r < TEXW; ++r) dst[r] = (_Float16)0.0f;
}

__device__ __forceinline__ int cell16(float x, float y, float z) {
    int qx = min(15, max(0, (int)(x * 16.0f)));
    int qy = min(15, max(0, (int)(y * 16.0f)));
    int qz = min(15, max(0, (int)(z * 16.0f)));
    return (qz << 8) | (qy << 4) | qx;   // x contiguous -> plane rows contiguous
}

// ---------------------------------------------------------------------------
// S1: per-block LDS histogram -> m[b*NB + k]   (row-contiguous per block)
// ---------------------------------------------------------------------------
__global__ __launch_bounds__(SORTT) void vme_hist(const float* __restrict__ xyz,
                                                  int* __restrict__ m, int n) {
    __shared__ int h[NB];
    int t = threadIdx.x, b = blockIdx.x;
    for (int k = t; k < NB; k += SORTT) h[k] = 0;
    __syncthreads();
    int P = (n + SORTB - 1) / SORTB;
    int lo = b * P, hi = min(n, lo + P);
    for (int i = lo + t; i < hi; i += SORTT) {
        float x = xyz[3 * (size_t)i + 0];
        float y = xyz[3 * (size_t)i + 1];
        float z = xyz[3 * (size_t)i + 2];
        atomicAdd(&h[cell16(x, y, z)], 1);
    }
    __syncthreads();
    for (int k = t; k < NB; k += SORTT) m[(size_t)b * NB + k] = h[k];
}

// ---------------------------------------------------------------------------
// S2a: per-bin exclusive scan over blocks (thread-per-bin; coalesced rows).
// ---------------------------------------------------------------------------
__global__ __launch_bounds__(256) void vme_scan_cols(int* __restrict__ m,
                                                     int* __restrict__ T) {
    int k = blockIdx.x * 256 + threadIdx.x;   // 0..NB-1, grid = NB/256
    int run = 0;
#pragma unroll 8
    for (int b = 0; b < SORTB; ++b) {
        size_t p = (size_t)b * NB + k;
        int v = m[p];
        m[p] = run;
        run += v;
    }
    T[k] = run;
}

// ---------------------------------------------------------------------------
// S2b: exclusive scan of the NB bin totals (one block)
// ---------------------------------------------------------------------------
__global__ __launch_bounds__(1024) void vme_scan_bins(int* __restrict__ T) {
    __shared__ int sh[1024];
    int t = threadIdx.x;
    int base = t * (NB / 1024);
    int l[NB / 1024];
    int s = 0;
#pragma unroll
    for (int k = 0; k < NB / 1024; ++k) { l[k] = T[base + k]; s += l[k]; }
    sh[t] = s;
    __syncthreads();
    for (int off = 1; off < 1024; off <<= 1) {
        int u = sh[t];
        int add = (t >= off) ? sh[t - off] : 0;
        __syncthreads();
        sh[t] = u + add;
        __syncthreads();
    }
    int run = sh[t] - s;   // exclusive
#pragma unroll
    for (int k = 0; k < NB / 1024; ++k) { T[base + k] = run; run += l[k]; }
}

// ---------------------------------------------------------------------------
// S3: scatter via LDS ranks; base = m[b*NB+k] + T[k]. No global atomics.
// ---------------------------------------------------------------------------
__global__ __launch_bounds__(SORTT) void vme_scatter(const float* __restrict__ xyz,
                                                     const int* __restrict__ m,
                                                     const int* __restrict__ T,
                                                     f32x4* __restrict__ sorted, int n) {
    __shared__ int bases[NB];
    __shared__ int ranks[NB];
    int t = threadIdx.x, b = blockIdx.x;
    for (int k = t; k < NB; k += SORTT) {
        bases[k] = m[(size_t)b * NB + k] + T[k];
        ranks[k] = 0;
    }
    __syncthreads();
    int P = (n + SORTB - 1) / SORTB;
    int lo = b * P, hi = min(n, lo + P);
    for (int i = lo + t; i < hi; i += SORTT) {
        float x = xyz[3 * (size_t)i + 0];
        float y = xyz[3 * (size_t)i + 1];
        float z = xyz[3 * (size_t)i + 2];
        int c = cell16(x, y, z);
        int r = atomicAdd(&ranks[c], 1);
        f32x4 v = {x, y, z, __uint_as_float((unsigned)i)};
        sorted[bases[c] + r] = v;
    }
}

// ---------------------------------------------------------------------------
// Main kernel: one block per cell. Stage the cell's 14x14 tap region of each
// plane into LDS (from L2-resident planes), then all taps are LDS reads.
// ---------------------------------------------------------------------------
__global__ __launch_bounds__(256) void vme_main_cells(const f32x4* __restrict__ sorted,
                                                      const _Float16* __restrict__ tp,
                                                      const unsigned* __restrict__ w2u,
                                                      const int* __restrict__ T,
                                                      float* __restrict__ out, int n) {
    __shared__ _Float16 lds[3 * REG * REGP * TEXW];   // 21504 B
    int k = blockIdx.x;
    int qx = k & 15, qy = (k >> 4) & 15, qz = k >> 8;

    int rux = (qx * (RES - 1)) >> 4;   // region origin per axis
    int ruy = (qy * (RES - 1)) >> 4;
    int ruz = (qz * (RES - 1)) >> 4;
    int ru[3] = {rux, rux, ruy};       // plane u-origin (x,x,y)
    int rv[3] = {ruy, ruz, ruz};       // plane v-origin (y,z,z)

    int t = threadIdx.x;
    // stage 3 * 14 * 14 = 588 texels (32 B each), coalesced rows
    for (int tix = t; tix < 3 * REG * REG; tix += 256) {
        int p = tix / (REG * REG);
        int rem = tix - p * (REG * REG);
        int vy = rem / REG, vx = rem - vy * REG;
        int gx = min(ru[p] + vx, RES - 1);
        int gy = min(rv[p] + vy, RES - 1);
        const _Float16* src = tp + ((size_t)p * NHW + (size_t)(gy * RES + gx)) * TEXW;
        _Float16* dst = lds + (size_t)((p * REG + vy) * REGP + vx) * TEXW;
        *(uint4*)dst = *(const uint4*)src;
        *(uint2*)(dst + 8) = *(const uint2*)(src + 8);
    }
    __syncthreads();

    int lo = T[k];
    int hi = (k == NB - 1) ? n : T[k + 1];

    for (int j = lo + t; j < hi; j += 256) {
        f32x4 s = sorted[j];
        unsigned idx = __float_as_uint(s.w);
        float us[3] = {s.x, s.x, s.y};
        float vs[3] = {s.y, s.z, s.z};

        h2 f2[NF / 2];
#pragma unroll
        for (int p = 0; p < 3; ++p) {
            float x = us[p] * (float)(RES - 1);
            float y = vs[p] * (float)(RES - 1);
            x = fminf(fmaxf(x, 0.0f), (float)(RES - 1));
            y = fminf(fmaxf(y, 0.0f), (float)(RES - 1));
            int x0 = (int)x;
            int y0 = (int)y;
            int x1 = min(x0 + 1, RES - 1);
            int y1 = min(y0 + 1, RES - 1);
            float wx = x - (float)x0;
            float wy = y - (float)y0;
            int lx0 = x0 - ru[p], lx1 = x1 - ru[p];
            int ly0 = y0 - rv[p], ly1 = y1 - rv[p];

            _Float16 hw00 = (_Float16)((1.0f - wx) * (1.0f - wy));
            _Float16 hw01 = (_Float16)(wx * (1.0f - wy));
            _Float16 hw10 = (_Float16)((1.0f - wx) * wy);
            _Float16 hw11 = (_Float16)(wx * wy);
            h2 h00 = {hw00, hw00}, h01 = {hw01, hw01}, h10 = {hw10, hw10}, h11 = {hw11, hw11};

            const _Float16* base = lds + (size_t)(p * REG * REGP) * TEXW;
            const _Float16* t00 = base + (size_t)(ly0 * REGP + lx0) * TEXW;
            const _Float16* t01 = base + (size_t)(ly0 * REGP + lx1) * TEXW;
            const _Float16* t10 = base + (size_t)(ly1 * REGP + lx0) * TEXW;
            const _Float16* t11 = base + (size_t)(ly1 * REGP + lx1) * TEXW;

            union TexA { uint4 v; h2 h[4]; } a00, a01, a10, a11;
            union TexB { uint2 v; h2 h[2]; } b00, b01, b10, b11;
            a00.v = *(const uint4*)(t00);  b00.v = *(const uint2*)(t00 + 8);
            a01.v = *(const uint4*)(t01);  b01.v = *(const uint2*)(t01 + 8);
            a10.v = *(const uint4*)(t10);  b10.v = *(const uint2*)(t10 + 8);
            a11.v = *(const uint4*)(t11);  b11.v = *(const uint2*)(t11 + 8);

#pragma unroll
            for (int q = 0; q < 4; ++q)
                f2[p * 6 + q] = a00.h[q] * h00 + a01.h[q] * h01 + a10.h[q] * h10 + a11.h[q] * h11;
#pragma unroll
            for (int q = 0; q < 2; ++q)
                f2[p * 6 + 4 + q] = b00.h[q] * h00 + b01.h[q] * h01 + b10.h[q] * h10 + b11.h[q] * h11;
        }

        float acc[ODIM];
#pragma unroll
        for (int o = 0; o < ODIM; ++o) {
            float sum = 0.0f;
#pragma unroll
            for (int kk = 0; kk < NF / 2; ++kk) {
                union { unsigned u; h2 h; } cv;
                cv.u = w2u[o * (NF / 2) + kk];
                sum = fdot2(f2[kk], cv.h, sum);
            }
            acc[o] = sum;
        }

        float* op = out + (size_t)idx * ODIM;
#pragma unroll
        for (int q = 0; q < 8; ++q) {
            f32x4 v = {acc[4 * q + 0], acc[4 * q + 1], acc[4 * q + 2], acc[4 * q + 3]};
            *(f32x4*)(op + 4 * q) = v;
        }
    }
}

// ---------------------------------------------------------------------------
// Fallbacks (f32 weights)
// ---------------------------------------------------------------------------
__device__ __forceinline__ void decode_texel(const _Float16* __restrict__ tex, float* __restrict__ o) {
    union { uint4 v; _Float16 h[8]; } A;
    union { uint2 v; _Float16 h[4]; } B;
    A.v = *(const uint4*)(tex);
    B.v = *(const uint2*)(tex + 8);
#pragma unroll
    for (int r = 0; r < 8; ++r) o[r] = (float)A.h[r];
#pragma unroll
    for (int r = 0; r < 4; ++r) o[8 + r] = (float)B.h[r];
}

__device__ __forceinline__ void vme_compute_point(float px, float py, float pz,
                                                  const _Float16* __restrict__ tp,
                                                  const float* __restrict__ w,
                                                  float* __restrict__ op) {
    float f[NF];
    float us[3] = {px, px, py};
    float vs[3] = {py, pz, pz};
#pragma unroll
    for (int p = 0; p < 3; ++p) {
        float x = us[p] * (float)(RES - 1);
        float y = vs[p] * (float)(RES - 1);
        x = fminf(fmaxf(x, 0.0f), (float)(RES - 1));
        y = fminf(fmaxf(y, 0.0f), (float)(RES - 1));
        int x0 = (int)x, y0 = (int)y;
        int x1 = min(x0 + 1, RES - 1), y1 = min(y0 + 1, RES - 1);
        float wx = x - (float)x0, wy = y - (float)y0;
        float w00 = (1.0f - wx) * (1.0f - wy), w01 = wx * (1.0f - wy);
        float w10 = (1.0f - wx) * wy, w11 = wx * wy;
        const _Float16* base = tp + (size_t)p * NHW * TEXW;
        float d00[RANK], d01[RANK], d10[RANK], d11[RANK];
        decode_texel(base + (size_t)(y0 * RES + x0) * TEXW, d00);
        decode_texel(base + (size_t)(y0 * RES + x1) * TEXW, d01);
        decode_texel(base + (size_t)(y1 * RES + x0) * TEXW, d10);
        decode_texel(base + (size_t)(y1 * RES + x1) * TEXW, d11);
#pragma unroll
        for (int r = 0; r < RANK; ++r)
            f[p * RANK + r] = w00 * d00[r] + w01 * d01[r] + w10 * d10[r] + w11 * d11[r];
    }
    float acc[ODIM];
#pragma unroll
    for (int o = 0; o < ODIM; ++o) {
        float s = 0.0f;
#pragma unroll
        for (int k = 0; k < NF; ++k) s += f[k] * w[o * NF + k];
        acc[o] = s;
    }
#pragma unroll
    for (int q = 0; q < 8; ++q) {
        f32x4 v = {acc[4 * q + 0], acc[4 * q + 1], acc[4 * q + 2], acc[4 * q + 3]};
        *(f32x4*)(op + 4 * q) = v;
    }
}

__global__ __launch_bounds__(256) void vme_main(const float* __restrict__ xyz,
                                                const _Float16* __restrict__ tp,
                                                const float* __restrict__ w,
                                                float* __restrict__ out, int n) {
    int i = blockIdx.x * 256 + threadIdx.x;
    if (i >= n) return;
    vme_compute_point(xyz[3 * (size_t)i], xyz[3 * (size_t)i + 1], xyz[3 * (size_t)i + 2],
                      tp, w, out + (size_t)i * ODIM);
}

__global__ __launch_bounds__(256) void vme_main_fb(const float* __restrict__ xyz,
                                                   const float* __restrict__ pa,
                                                   const float* __restrict__ pb,
                                                   const float* __restrict__ pc,
                                                   const float* __restrict__ w,
                                                   float* __restrict__ out, int n) {
    int i = blockIdx.x * 256 + threadIdx.x;
    if (i >= n) return;
    float px = xyz[3 * (size_t)i + 0];
    float py = xyz[3 * (size_t)i + 1];
    float pz = xyz[3 * (size_t)i + 2];
    float f[NF];
    float us[3] = {px, px, py};
    float vs[3] = {py, pz, pz};
#pragma unroll
    for (int p = 0; p < 3; ++p) {
        float x = us[p] * (float)(RES - 1);
        float y = vs[p] * (float)(RES - 1);
        x = fminf(fmaxf(x, 0.0f), (float)(RES - 1));
        y = fminf(fmaxf(y, 0.0f), (float)(RES - 1));
        int x0 = (int)x, y0 = (int)y;
        int x1 = min(x0 + 1, RES - 1), y1 = min(y0 + 1, RES - 1);
        float wx = x - (float)x0, wy = y - (float)y0;
        float w00 = (1.0f - wx) * (1.0f - wy), w01 = wx * (1.0f - wy);
        float w10 = (1.0f - wx) * wy, w11 = wx * wy;
        const float* base = (p == 0) ? pa : (p == 1) ? pb : pc;
        int i00 = y0 * RES + x0, i01 = y0 * RES + x1;
        int i10 = y1 * RES + x0, i11 = y1 * RES + x1;
#pragma unroll
        for (int r = 0; r < RANK; ++r) {
            const float* pr = base + (size_t)r * NHW;
            f[p * RANK + r] = w00 * pr[i00] + w01 * pr[i01] + w10 * pr[i10] + w11 * pr[i11];
        }
    }
    float acc[ODIM];
#pragma unroll
    for (int o = 0; o < ODIM; ++o) {
        float s = 0.0f;
#pragma unroll
        for (int k = 0; k < NF; ++k) s += f[k] * w[o * NF + k];
        acc[o] = s;
    }
    float4* op = (float4*)(out + (size_t)i * ODIM);
#pragma unroll
    for (int q = 0; q < 8; ++q)
        op[q] = make_float4(acc[4 * q], acc[4 * q + 1], acc[4 * q + 2], acc[4 * q + 3]);
}

extern "C" void kernel_launch(void* const* d_in, const int* in_sizes, int n_in,
                              void* d_out, int out_size, void* d_ws, size_t ws_size,
                              hipStream_t stream) {
    const float* xyz = (const float*)d_in[0];
    const float* xy  = (const float*)d_in[1];
    const float* xz  = (const float*)d_in[2];
    const float* yz  = (const float*)d_in[3];
    const float* wml = (const float*)d_in[4];
    float* out = (float*)d_out;

    int n = in_sizes[0] / 3;
    int nblk = (n + 255) / 256;
    int tblk = (3 * NHW + 255) / 256;

    const size_t TPB      = (size_t)3 * NHW * TEXW * sizeof(_Float16);  // 3,538,944
    const size_t OFF_W2   = TPB;                                        // 2304 B (pad 4K)
    const size_t OFF_HIST = TPB + 4096;                                 // 4 MB matrix
    const size_t OFF_T    = OFF_HIST + (size_t)NB * SORTB * 4;          // 16 KB
    const size_t OFF_SORT = OFF_T + (size_t)NB * 4;
    const size_t WS_SORTED = OFF_SORT + (size_t)n * 16;

    char* ws = (char*)d_ws;

    if (d_ws && ws_size >= WS_SORTED) {
        _Float16* tp   = (_Float16*)(ws);
        unsigned* w2u  = (unsigned*)(ws + OFF_W2);
        int*      m    = (int*)(ws + OFF_HIST);
        int*      T    = (int*)(ws + OFF_T);
        f32x4*    srt  = (f32x4*)(ws + OFF_SORT);

        vme_transpose<<<tblk, 256, 0, stream>>>(xy, xz, yz, wml, tp, w2u);
        vme_hist<<<SORTB, SORTT, 0, stream>>>(xyz, m, n);
        vme_scan_cols<<<NB / 256, 256, 0, stream>>>(m, T);
        vme_scan_bins<<<1, 1024, 0, stream>>>(T);
        vme_scatter<<<SORTB, SORTT, 0, stream>>>(xyz, m, T, srt, n);
        vme_main_cells<<<NB, 256, 0, stream>>>(srt, tp, w2u, T, out, n);
    } else if (d_ws && ws_size >= TPB) {
        _Float16* tp = (_Float16*)ws;
        vme_transpose<<<tblk, 256, 0, stream>>>(xy, xz, yz, wml, tp, (unsigned*)nullptr);
        vme_main<<<nblk, 256, 0, stream>>>(xyz, tp, wml, out, n);
    } else {
        vme_main_fb<<<nblk, 256, 0, stream>>>(xyz, xy, xz, yz, wml, out, n);
    }
}

// Round 10
// 192.141 us; speedup vs baseline: 1.7441x; 1.7441x over previous
//
#include <hip/hip_runtime.h>
#include <hip/hip_fp16.h>

#define RANK 12
#define RES 192
#define NHW (RES * RES)
#define NF 36
#define ODIM 32
#define TEXW 16            // halfs per texel (12 used + 4 pad) -> 32 B
// coarse sort (fallback tier)
#define NB 4096            // 16^3
#define SORTB 256
#define SORTT 1024
// fine sort (primary tier)
#define NB2 32768          // 32^3
#define RSHIFT 22          // rank packed above 22 bits; base < 2^22 (n < 4.19M)

typedef float f32x4 __attribute__((ext_vector_type(4)));
typedef _Float16 h2 __attribute__((ext_vector_type(2)));

__device__ __forceinline__ float fdot2(h2 a, h2 b, float c) {
#if __has_builtin(__builtin_amdgcn_fdot2)
    return __builtin_amdgcn_fdot2(a, b, c, false);
#else
    return c + (float)a.x * (float)b.x + (float)a.y * (float)b.y;
#endif
}

// ---------------------------------------------------------------------------
// Pre-pass: planes [R][H][W] f32 -> [3][H][W][16] fp16 (3.54 MB, L2-resident)
// + pack w_mlp into half2 words (576 u32) when w2u != nullptr
// ---------------------------------------------------------------------------
__global__ __launch_bounds__(256) void vme_transpose(const float* __restrict__ a,
                                                     const float* __restrict__ b,
                                                     const float* __restrict__ c,
                                                     const float* __restrict__ w,
                                                     _Float16* __restrict__ t,
                                                     unsigned* __restrict__ w2u) {
    int idx = blockIdx.x * 256 + threadIdx.x;
    if (w2u != nullptr && idx < ODIM * NF / 2) {
        int o = idx / (NF / 2), k = idx - o * (NF / 2);
        union { h2 h; unsigned u; } cv;
        cv.h.x = (_Float16)w[o * NF + 2 * k];
        cv.h.y = (_Float16)w[o * NF + 2 * k + 1];
        w2u[idx] = cv.u;
    }
    if (idx >= 3 * NHW) return;
    int p = idx / NHW;
    int yx = idx - p * NHW;
    const float* src = (p == 0) ? a : (p == 1) ? b : c;
    _Float16* dst = t + (size_t)idx * TEXW;
#pragma unroll
    for (int r = 0; r < RANK; ++r) dst[r] = (_Float16)src[(size_t)r * NHW + yx];
#pragma unroll
    for (int r = RANK; r < TEXW; ++r) dst[r] = (_Float16)0.0f;
}

__device__ __forceinline__ int cell16(float x, float y, float z) {
    int qx = min(15, max(0, (int)(x * 16.0f)));
    int qy = min(15, max(0, (int)(y * 16.0f)));
    int qz = min(15, max(0, (int)(z * 16.0f)));
    return (qz << 8) | (qy << 4) | qx;
}

__device__ __forceinline__ int cell32(float x, float y, float z) {
    int qx = min(31, max(0, (int)(x * 32.0f)));
    int qy = min(31, max(0, (int)(y * 32.0f)));
    int qz = min(31, max(0, (int)(z * 32.0f)));
    return (qz << 10) | (qy << 5) | qx;   // x contiguous -> plane rows contiguous
}

// ============================ fine (32^3) sort =============================
// S1: per-block u32 LDS histogram -> u16 matrix m[b*NB2 + k]
__global__ __launch_bounds__(SORTT) void vme_hist32(const float* __restrict__ xyz,
                                                    unsigned short* __restrict__ m, int n) {
    __shared__ unsigned h[NB2];           // 128 KB
    int t = threadIdx.x, b = blockIdx.x;
    for (int k = t; k < NB2; k += SORTT) h[k] = 0;
    __syncthreads();
    int P = (n + SORTB - 1) / SORTB;
    int lo = b * P, hi = min(n, lo + P);
    for (int i = lo + t; i < hi; i += SORTT) {
        float x = xyz[3 * (size_t)i + 0];
        float y = xyz[3 * (size_t)i + 1];
        float z = xyz[3 * (size_t)i + 2];
        atomicAdd(&h[cell32(x, y, z)], 1u);
    }
    __syncthreads();
    for (int k = t; k < NB2; k += SORTT) m[(size_t)b * NB2 + k] = (unsigned short)h[k];
}

// S2a: per-bin exclusive scan over blocks, in place on u16 matrix; totals to T.
__global__ __launch_bounds__(256) void vme_scan_cols32(unsigned short* __restrict__ m,
                                                       int* __restrict__ T) {
    int k = blockIdx.x * 256 + threadIdx.x;   // grid = NB2/256 = 128
    unsigned run = 0;
#pragma unroll 8
    for (int b = 0; b < SORTB; ++b) {
        size_t p = (size_t)b * NB2 + k;
        unsigned v = m[p];
        m[p] = (unsigned short)run;
        run += v;
    }
    T[k] = (int)run;
}

// S2b: exclusive scan of NB2 bin totals (one block, 32/thread)
__global__ __launch_bounds__(1024) void vme_scan_bins32(int* __restrict__ T) {
    __shared__ int sh[1024];
    int t = threadIdx.x;
    int base = t * (NB2 / 1024);
    int l[NB2 / 1024];
    int s = 0;
#pragma unroll
    for (int k = 0; k < NB2 / 1024; ++k) { l[k] = T[base + k]; s += l[k]; }
    sh[t] = s;
    __syncthreads();
    for (int off = 1; off < 1024; off <<= 1) {
        int u = sh[t];
        int add = (t >= off) ? sh[t - off] : 0;
        __syncthreads();
        sh[t] = u + add;
        __syncthreads();
    }
    int run = sh[t] - s;
#pragma unroll
    for (int k = 0; k < NB2 / 1024; ++k) { T[base + k] = run; run += l[k]; }
}

// S3: scatter; LDS u32 packs base(low 22b) | rank counter(high bits)
__global__ __launch_bounds__(SORTT) void vme_scatter32(const float* __restrict__ xyz,
                                                       const unsigned short* __restrict__ m,
                                                       const int* __restrict__ T,
                                                       f32x4* __restrict__ sorted, int n) {
    __shared__ unsigned arr[NB2];         // 128 KB
    int t = threadIdx.x, b = blockIdx.x;
    for (int k = t; k < NB2; k += SORTT)
        arr[k] = (unsigned)((int)m[(size_t)b * NB2 + k] + T[k]);
    __syncthreads();
    int P = (n + SORTB - 1) / SORTB;
    int lo = b * P, hi = min(n, lo + P);
    for (int i = lo + t; i < hi; i += SORTT) {
        float x = xyz[3 * (size_t)i + 0];
        float y = xyz[3 * (size_t)i + 1];
        float z = xyz[3 * (size_t)i + 2];
        int c = cell32(x, y, z);
        unsigned old = atomicAdd(&arr[c], 1u << RSHIFT);
        unsigned pos = (old & ((1u << RSHIFT) - 1u)) + (old >> RSHIFT);
        f32x4 v = {x, y, z, __uint_as_float((unsigned)i)};
        sorted[pos] = v;
    }
}

// ============================ coarse (16^3) sort ===========================
__global__ __launch_bounds__(SORTT) void vme_hist(const float* __restrict__ xyz,
                                                  int* __restrict__ m, int n) {
    __shared__ int h[NB];
    int t = threadIdx.x, b = blockIdx.x;
    for (int k = t; k < NB; k += SORTT) h[k] = 0;
    __syncthreads();
    int P = (n + SORTB - 1) / SORTB;
    int lo = b * P, hi = min(n, lo + P);
    for (int i = lo + t; i < hi; i += SORTT) {
        float x = xyz[3 * (size_t)i + 0];
        float y = xyz[3 * (size_t)i + 1];
        float z = xyz[3 * (size_t)i + 2];
        atomicAdd(&h[cell16(x, y, z)], 1);
    }
    __syncthreads();
    for (int k = t; k < NB; k += SORTT) m[(size_t)b * NB + k] = h[k];
}

__global__ __launch_bounds__(256) void vme_scan_cols(int* __restrict__ m,
                                                     int* __restrict__ T) {
    int k = blockIdx.x * 256 + threadIdx.x;
    int run = 0;
#pragma unroll 8
    for (int b = 0; b < SORTB; ++b) {
        size_t p = (size_t)b * NB + k;
        int v = m[p];
        m[p] = run;
        run += v;
    }
    T[k] = run;
}

__global__ __launch_bounds__(1024) void vme_scan_bins(int* __restrict__ T) {
    __shared__ int sh[1024];
    int t = threadIdx.x;
    int base = t * (NB / 1024);
    int l[NB / 1024];
    int s = 0;
#pragma unroll
    for (int k = 0; k < NB / 1024; ++k) { l[k] = T[base + k]; s += l[k]; }
    sh[t] = s;
    __syncthreads();
    for (int off = 1; off < 1024; off <<= 1) {
        int u = sh[t];
        int add = (t >= off) ? sh[t - off] : 0;
        __syncthreads();
        sh[t] = u + add;
        __syncthreads();
    }
    int run = sh[t] - s;
#pragma unroll
    for (int k = 0; k < NB / 1024; ++k) { T[base + k] = run; run += l[k]; }
}

__global__ __launch_bounds__(SORTT) void vme_scatter(const float* __restrict__ xyz,
                                                     const int* __restrict__ m,
                                                     const int* __restrict__ T,
                                                     f32x4* __restrict__ sorted, int n) {
    __shared__ int bases[NB];
    __shared__ int ranks[NB];
    int t = threadIdx.x, b = blockIdx.x;
    for (int k = t; k < NB; k += SORTT) {
        bases[k] = m[(size_t)b * NB + k] + T[k];
        ranks[k] = 0;
    }
    __syncthreads();
    int P = (n + SORTB - 1) / SORTB;
    int lo = b * P, hi = min(n, lo + P);
    for (int i = lo + t; i < hi; i += SORTT) {
        float x = xyz[3 * (size_t)i + 0];
        float y = xyz[3 * (size_t)i + 1];
        float z = xyz[3 * (size_t)i + 2];
        int c = cell16(x, y, z);
        int r = atomicAdd(&ranks[c], 1);
        f32x4 v = {x, y, z, __uint_as_float((unsigned)i)};
        sorted[bases[c] + r] = v;
    }
}

// ---------------------------------------------------------------------------
// Main kernel (sorted, flat — R8-proven): packed fp16 interp + v_dot2 MLP.
// ---------------------------------------------------------------------------
__global__ __launch_bounds__(256) void vme_main_sorted(const f32x4* __restrict__ sorted,
                                                       const _Float16* __restrict__ tp,
                                                       const unsigned* __restrict__ w2u,
                                                       float* __restrict__ out, int n) {
    int j = blockIdx.x * 256 + threadIdx.x;
    if (j >= n) return;
    f32x4 s = sorted[j];
    unsigned idx = __float_as_uint(s.w);
    float px = s.x, py = s.y, pz = s.z;

    h2 f2[NF / 2];
    float us[3] = {px, px, py};
    float vs[3] = {py, pz, pz};

#pragma unroll
    for (int p = 0; p < 3; ++p) {
        float x = us[p] * (float)(RES - 1);
        float y = vs[p] * (float)(RES - 1);
        x = fminf(fmaxf(x, 0.0f), (float)(RES - 1));
        y = fminf(fmaxf(y, 0.0f), (float)(RES - 1));
        int x0 = (int)x;
        int y0 = (int)y;
        int x1 = min(x0 + 1, RES - 1);
        int y1 = min(y0 + 1, RES - 1);
        float wx = x - (float)x0;
        float wy = y - (float)y0;
        _Float16 hw00 = (_Float16)((1.0f - wx) * (1.0f - wy));
        _Float16 hw01 = (_Float16)(wx * (1.0f - wy));
        _Float16 hw10 = (_Float16)((1.0f - wx) * wy);
        _Float16 hw11 = (_Float16)(wx * wy);
        h2 h00 = {hw00, hw00}, h01 = {hw01, hw01}, h10 = {hw10, hw10}, h11 = {hw11, hw11};

        const _Float16* base = tp + (size_t)p * NHW * TEXW;
        const _Float16* t00 = base + (size_t)(y0 * RES + x0) * TEXW;
        const _Float16* t01 = base + (size_t)(y0 * RES + x1) * TEXW;
        const _Float16* t10 = base + (size_t)(y1 * RES + x0) * TEXW;
        const _Float16* t11 = base + (size_t)(y1 * RES + x1) * TEXW;

        union TexA { uint4 v; h2 h[4]; } a00, a01, a10, a11;
        union TexB { uint2 v; h2 h[2]; } b00, b01, b10, b11;
        a00.v = *(const uint4*)(t00);  b00.v = *(const uint2*)(t00 + 8);
        a01.v = *(const uint4*)(t01);  b01.v = *(const uint2*)(t01 + 8);
        a10.v = *(const uint4*)(t10);  b10.v = *(const uint2*)(t10 + 8);
        a11.v = *(const uint4*)(t11);  b11.v = *(const uint2*)(t11 + 8);

#pragma unroll
        for (int q = 0; q < 4; ++q)
            f2[p * 6 + q] = a00.h[q] * h00 + a01.h[q] * h01 + a10.h[q] * h10 + a11.h[q] * h11;
#pragma unroll
        for (int q = 0; q < 2; ++q)
            f2[p * 6 + 4 + q] = b00.h[q] * h00 + b01.h[q] * h01 + b10.h[q] * h10 + b11.h[q] * h11;
    }

    float acc[ODIM];
#pragma unroll
    for (int o = 0; o < ODIM; ++o) {
        float sum = 0.0f;
#pragma unroll
        for (int k = 0; k < NF / 2; ++k) {
            union { unsigned u; h2 h; } cv;
            cv.u = w2u[o * (NF / 2) + k];
            sum = fdot2(f2[k], cv.h, sum);
        }
        acc[o] = sum;
    }

    float* op = out + (size_t)idx * ODIM;
#pragma unroll
    for (int q = 0; q < 8; ++q) {
        f32x4 v = {acc[4 * q + 0], acc[4 * q + 1], acc[4 * q + 2], acc[4 * q + 3]};
        *(f32x4*)(op + 4 * q) = v;
    }
}

// ---------------------------------------------------------------------------
// Fallbacks (f32 weights)
// ---------------------------------------------------------------------------
__device__ __forceinline__ void decode_texel(const _Float16* __restrict__ tex, float* __restrict__ o) {
    union { uint4 v; _Float16 h[8]; } A;
    union { uint2 v; _Float16 h[4]; } B;
    A.v = *(const uint4*)(tex);
    B.v = *(const uint2*)(tex + 8);
#pragma unroll
    for (int r = 0; r < 8; ++r) o[r] = (float)A.h[r];
#pragma unroll
    for (int r = 0; r < 4; ++r) o[8 + r] = (float)B.h[r];
}

__device__ __forceinline__ void vme_compute_point(float px, float py, float pz,
                                                  const _Float16* __restrict__ tp,
                                                  const float* __restrict__ w,
                                                  float* __restrict__ op) {
    float f[NF];
    float us[3] = {px, px, py};
    float vs[3] = {py, pz, pz};
#pragma unroll
    for (int p = 0; p < 3; ++p) {
        float x = us[p] * (float)(RES - 1);
        float y = vs[p] * (float)(RES - 1);
        x = fminf(fmaxf(x, 0.0f), (float)(RES - 1));
        y = fminf(fmaxf(y, 0.0f), (float)(RES - 1));
        int x0 = (int)x, y0 = (int)y;
        int x1 = min(x0 + 1, RES - 1), y1 = min(y0 + 1, RES - 1);
        float wx = x - (float)x0, wy = y - (float)y0;
        float w00 = (1.0f - wx) * (1.0f - wy), w01 = wx * (1.0f - wy);
        float w10 = (1.0f - wx) * wy, w11 = wx * wy;
        const _Float16* base = tp + (size_t)p * NHW * TEXW;
        float d00[RANK], d01[RANK], d10[RANK], d11[RANK];
        decode_texel(base + (size_t)(y0 * RES + x0) * TEXW, d00);
        decode_texel(base + (size_t)(y0 * RES + x1) * TEXW, d01);
        decode_texel(base + (size_t)(y1 * RES + x0) * TEXW, d10);
        decode_texel(base + (size_t)(y1 * RES + x1) * TEXW, d11);
#pragma unroll
        for (int r = 0; r < RANK; ++r)
            f[p * RANK + r] = w00 * d00[r] + w01 * d01[r] + w10 * d10[r] + w11 * d11[r];
    }
    float acc[ODIM];
#pragma unroll
    for (int o = 0; o < ODIM; ++o) {
        float s = 0.0f;
#pragma unroll
        for (int k = 0; k < NF; ++k) s += f[k] * w[o * NF + k];
        acc[o] = s;
    }
#pragma unroll
    for (int q = 0; q < 8; ++q) {
        f32x4 v = {acc[4 * q + 0], acc[4 * q + 1], acc[4 * q + 2], acc[4 * q + 3]};
        *(f32x4*)(op + 4 * q) = v;
    }
}

__global__ __launch_bounds__(256) void vme_main(const float* __restrict__ xyz,
                                                const _Float16* __restrict__ tp,
                                                const float* __restrict__ w,
                                                float* __restrict__ out, int n) {
    int i = blockIdx.x * 256 + threadIdx.x;
    if (i >= n) return;
    vme_compute_point(xyz[3 * (size_t)i], xyz[3 * (size_t)i + 1], xyz[3 * (size_t)i + 2],
                      tp, w, out + (size_t)i * ODIM);
}

__global__ __launch_bounds__(256) void vme_main_fb(const float* __restrict__ xyz,
                                                   const float* __restrict__ pa,
                                                   const float* __restrict__ pb,
                                                   const float* __restrict__ pc,
                                                   const float* __restrict__ w,
                                                   float* __restrict__ out, int n) {
    int i = blockIdx.x * 256 + threadIdx.x;
    if (i >= n) return;
    float px = xyz[3 * (size_t)i + 0];
    float py = xyz[3 * (size_t)i + 1];
    float pz = xyz[3 * (size_t)i + 2];
    float f[NF];
    float us[3] = {px, px, py};
    float vs[3] = {py, pz, pz};
#pragma unroll
    for (int p = 0; p < 3; ++p) {
        float x = us[p] * (float)(RES - 1);
        float y = vs[p] * (float)(RES - 1);
        x = fminf(fmaxf(x, 0.0f), (float)(RES - 1));
        y = fminf(fmaxf(y, 0.0f), (float)(RES - 1));
        int x0 = (int)x, y0 = (int)y;
        int x1 = min(x0 + 1, RES - 1), y1 = min(y0 + 1, RES - 1);
        float wx = x - (float)x0, wy = y - (float)y0;
        float w00 = (1.0f - wx) * (1.0f - wy), w01 = wx * (1.0f - wy);
        float w10 = (1.0f - wx) * wy, w11 = wx * wy;
        const float* base = (p == 0) ? pa : (p == 1) ? pb : pc;
        int i00 = y0 * RES + x0, i01 = y0 * RES + x1;
        int i10 = y1 * RES + x0, i11 = y1 * RES + x1;
#pragma unroll
        for (int r = 0; r < RANK; ++r) {
            const float* pr = base + (size_t)r * NHW;
            f[p * RANK + r] = w00 * pr[i00] + w01 * pr[i01] + w10 * pr[i10] + w11 * pr[i11];
        }
    }
    float acc[ODIM];
#pragma unroll
    for (int o = 0; o < ODIM; ++o) {
        float s = 0.0f;
#pragma unroll
        for (int k = 0; k < NF; ++k) s += f[k] * w[o * NF + k];
        acc[o] = s;
    }
    float4* op = (float4*)(out + (size_t)i * ODIM);
#pragma unroll
    for (int q = 0; q < 8; ++q)
        op[q] = make_float4(acc[4 * q], acc[4 * q + 1], acc[4 * q + 2], acc[4 * q + 3]);
}

extern "C" void kernel_launch(void* const* d_in, const int* in_sizes, int n_in,
                              void* d_out, int out_size, void* d_ws, size_t ws_size,
                              hipStream_t stream) {
    const float* xyz = (const float*)d_in[0];
    const float* xy  = (const float*)d_in[1];
    const float* xz  = (const float*)d_in[2];
    const float* yz  = (const float*)d_in[3];
    const float* wml = (const float*)d_in[4];
    float* out = (float*)d_out;

    int n = in_sizes[0] / 3;
    int nblk = (n + 255) / 256;
    int tblk = (3 * NHW + 255) / 256;

    const size_t TPB = (size_t)3 * NHW * TEXW * sizeof(_Float16);  // 3,538,944
    char* ws = (char*)d_ws;

    // fine (32^3) tier layout
    const size_t F_W2   = TPB;
    const size_t F_M    = TPB + 4096;
    const size_t F_T    = F_M + (size_t)SORTB * NB2 * 2;      // 16 MB matrix
    const size_t F_SORT = F_T + (size_t)NB2 * 4;
    const size_t F_END  = F_SORT + (size_t)n * 16;

    // coarse (16^3) tier layout
    const size_t C_W2   = TPB;
    const size_t C_M    = TPB + 4096;
    const size_t C_T    = C_M + (size_t)NB * SORTB * 4;       // 4 MB matrix
    const size_t C_SORT = C_T + (size_t)NB * 4;
    const size_t C_END  = C_SORT + (size_t)n * 16;

    if (d_ws && ws_size >= F_END) {
        _Float16*       tp  = (_Float16*)(ws);
        unsigned*       w2u = (unsigned*)(ws + F_W2);
        unsigned short* m   = (unsigned short*)(ws + F_M);
        int*            T   = (int*)(ws + F_T);
        f32x4*          srt = (f32x4*)(ws + F_SORT);

        vme_transpose<<<tblk, 256, 0, stream>>>(xy, xz, yz, wml, tp, w2u);
        vme_hist32<<<SORTB, SORTT, 0, stream>>>(xyz, m, n);
        vme_scan_cols32<<<NB2 / 256, 256, 0, stream>>>(m, T);
        vme_scan_bins32<<<1, 1024, 0, stream>>>(T);
        vme_scatter32<<<SORTB, SORTT, 0, stream>>>(xyz, m, T, srt, n);
        vme_main_sorted<<<nblk, 256, 0, stream>>>(srt, tp, w2u, out, n);
    } else if (d_ws && ws_size >= C_END) {
        _Float16* tp  = (_Float16*)(ws);
        unsigned* w2u = (unsigned*)(ws + C_W2);
        int*      m   = (int*)(ws + C_M);
        int*      T   = (int*)(ws + C_T);
        f32x4*    srt = (f32x4*)(ws + C_SORT);

        vme_transpose<<<tblk, 256, 0, stream>>>(xy, xz, yz, wml, tp, w2u);
        vme_hist<<<SORTB, SORTT, 0, stream>>>(xyz, m, n);
        vme_scan_cols<<<NB / 256, 256, 0, stream>>>(m, T);
        vme_scan_bins<<<1, 1024, 0, stream>>>(T);
        vme_scatter<<<SORTB, SORTT, 0, stream>>>(xyz, m, T, srt, n);
        vme_main_sorted<<<nblk, 256, 0, stream>>>(srt, tp, w2u, out, n);
    } else if (d_ws && ws_size >= TPB) {
        _Float16* tp = (_Float16*)ws;
        vme_transpose<<<tblk, 256, 0, stream>>>(xy, xz, yz, wml, tp, (unsigned*)nullptr);
        vme_main<<<nblk, 256, 0, stream>>>(xyz, tp, wml, out, n);
    } else {
        vme_main_fb<<<nblk, 256, 0, stream>>>(xyz, xy, xz, yz, wml, out, n);
    }
}

// Round 11
// 186.808 us; speedup vs baseline: 1.7939x; 1.0285x over previous
//
#include <hip/hip_runtime.h>
#include <hip/hip_fp16.h>

#define RANK 12
#define RES 192
#define NHW (RES * RES)
#define NF 36
#define ODIM 32
#define TEXW 16            // halfs per texel (12 used + 4 pad) -> 32 B
#define NB 4096            // 16^3 cells
#define SORTB 256          // sort blocks
#define SORTT 1024         // threads per sort block

typedef float f32x4 __attribute__((ext_vector_type(4)));
typedef _Float16 h2 __attribute__((ext_vector_type(2)));

__device__ __forceinline__ float fdot2(h2 a, h2 b, float c) {
#if __has_builtin(__builtin_amdgcn_fdot2)
    return __builtin_amdgcn_fdot2(a, b, c, false);
#else
    return c + (float)a.x * (float)b.x + (float)a.y * (float)b.y;
#endif
}

// ---------------------------------------------------------------------------
// Pre-pass: planes [R][H][W] f32 -> [3][H][W][16] fp16 (3.54 MB, L2-resident)
// + pack w_mlp into half2 words (576 u32) when w2u != nullptr
// ---------------------------------------------------------------------------
__global__ __launch_bounds__(256) void vme_transpose(const float* __restrict__ a,
                                                     const float* __restrict__ b,
                                                     const float* __restrict__ c,
                                                     const float* __restrict__ w,
                                                     _Float16* __restrict__ t,
                                                     unsigned* __restrict__ w2u) {
    int idx = blockIdx.x * 256 + threadIdx.x;
    if (w2u != nullptr && idx < ODIM * NF / 2) {
        int o = idx / (NF / 2), k = idx - o * (NF / 2);
        union { h2 h; unsigned u; } cv;
        cv.h.x = (_Float16)w[o * NF + 2 * k];
        cv.h.y = (_Float16)w[o * NF + 2 * k + 1];
        w2u[idx] = cv.u;
    }
    if (idx >= 3 * NHW) return;
    int p = idx / NHW;
    int yx = idx - p * NHW;
    const float* src = (p == 0) ? a : (p == 1) ? b : c;
    _Float16* dst = t + (size_t)idx * TEXW;
#pragma unroll
    for (int r = 0; r < RANK; ++r) dst[r] = (_Float16)src[(size_t)r * NHW + yx];
#pragma unroll
    for (int r = RANK; r < TEXW; ++r) dst[r] = (_Float16)0.0f;
}

__device__ __forceinline__ int cell16(float x, float y, float z) {
    int qx = min(15, max(0, (int)(x * 16.0f)));
    int qy = min(15, max(0, (int)(y * 16.0f)));
    int qz = min(15, max(0, (int)(z * 16.0f)));
    return (qz << 8) | (qy << 4) | qx;   // x contiguous -> plane rows contiguous
}

// ---------------------------------------------------------------------------
// S1: per-block LDS histogram with LDS-staged coalesced xyz reads.
// ---------------------------------------------------------------------------
__global__ __launch_bounds__(SORTT) void vme_hist(const float* __restrict__ xyz,
                                                  int* __restrict__ m, int n) {
    __shared__ int h[NB];               // 16 KB
    __shared__ float st[3 * SORTT];     // 12 KB
    int t = threadIdx.x, b = blockIdx.x;
    for (int k = t; k < NB; k += SORTT) h[k] = 0;
    int P = (n + SORTB - 1) / SORTB;
    int lo = b * P, hi = min(n, lo + P);
    for (int base = lo; base < hi; base += SORTT) {
        int cnt = min(SORTT, hi - base);
        int nf = 3 * cnt;
        __syncthreads();                 // st free of prior readers / h init done
        for (int q = t; q < nf; q += SORTT) st[q] = xyz[3 * (size_t)base + q];
        __syncthreads();
        if (t < cnt) {
            float x = st[3 * t], y = st[3 * t + 1], z = st[3 * t + 2];
            atomicAdd(&h[cell16(x, y, z)], 1);
        }
    }
    __syncthreads();
    for (int k = t; k < NB; k += SORTT) m[(size_t)b * NB + k] = h[k];
}

// ---------------------------------------------------------------------------
// S2a: per-bin exclusive scan over blocks (thread-per-bin; coalesced rows).
// ---------------------------------------------------------------------------
__global__ __launch_bounds__(256) void vme_scan_cols(int* __restrict__ m,
                                                     int* __restrict__ T) {
    int k = blockIdx.x * 256 + threadIdx.x;   // grid = NB/256
    int run = 0;
#pragma unroll 8
    for (int b = 0; b < SORTB; ++b) {
        size_t p = (size_t)b * NB + k;
        int v = m[p];
        m[p] = run;
        run += v;
    }
    T[k] = run;
}

// ---------------------------------------------------------------------------
// S2b: exclusive scan of the NB bin totals (one block)
// ---------------------------------------------------------------------------
__global__ __launch_bounds__(1024) void vme_scan_bins(int* __restrict__ T) {
    __shared__ int sh[1024];
    int t = threadIdx.x;
    int base = t * (NB / 1024);
    int l[NB / 1024];
    int s = 0;
#pragma unroll
    for (int k = 0; k < NB / 1024; ++k) { l[k] = T[base + k]; s += l[k]; }
    sh[t] = s;
    __syncthreads();
    for (int off = 1; off < 1024; off <<= 1) {
        int u = sh[t];
        int add = (t >= off) ? sh[t - off] : 0;
        __syncthreads();
        sh[t] = u + add;
        __syncthreads();
    }
    int run = sh[t] - s;
#pragma unroll
    for (int k = 0; k < NB / 1024; ++k) { T[base + k] = run; run += l[k]; }
}

// ---------------------------------------------------------------------------
// S3: scatter via LDS ranks + staged coalesced xyz reads. No global atomics.
// ---------------------------------------------------------------------------
__global__ __launch_bounds__(SORTT) void vme_scatter(const float* __restrict__ xyz,
                                                     const int* __restrict__ m,
                                                     const int* __restrict__ T,
                                                     f32x4* __restrict__ sorted, int n) {
    __shared__ int bases[NB];           // 16 KB
    __shared__ int ranks[NB];           // 16 KB
    __shared__ float st[3 * SORTT];     // 12 KB
    int t = threadIdx.x, b = blockIdx.x;
    for (int k = t; k < NB; k += SORTT) {
        bases[k] = m[(size_t)b * NB + k] + T[k];
        ranks[k] = 0;
    }
    int P = (n + SORTB - 1) / SORTB;
    int lo = b * P, hi = min(n, lo + P);
    for (int base = lo; base < hi; base += SORTT) {
        int cnt = min(SORTT, hi - base);
        int nf = 3 * cnt;
        __syncthreads();
        for (int q = t; q < nf; q += SORTT) st[q] = xyz[3 * (size_t)base + q];
        __syncthreads();
        if (t < cnt) {
            float x = st[3 * t], y = st[3 * t + 1], z = st[3 * t + 2];
            int c = cell16(x, y, z);
            int r = atomicAdd(&ranks[c], 1);
            f32x4 v = {x, y, z, __uint_as_float((unsigned)(base + t))};
            sorted[bases[c] + r] = v;
        }
    }
}

// ---------------------------------------------------------------------------
// Main kernel (sorted, flat — R8-proven): packed fp16 interp + v_dot2 MLP.
// ---------------------------------------------------------------------------
__global__ __launch_bounds__(256) void vme_main_sorted(const f32x4* __restrict__ sorted,
                                                       const _Float16* __restrict__ tp,
                                                       const unsigned* __restrict__ w2u,
                                                       float* __restrict__ out, int n) {
    int j = blockIdx.x * 256 + threadIdx.x;
    if (j >= n) return;
    f32x4 s = sorted[j];
    unsigned idx = __float_as_uint(s.w);
    float px = s.x, py = s.y, pz = s.z;

    h2 f2[NF / 2];
    float us[3] = {px, px, py};
    float vs[3] = {py, pz, pz};

#pragma unroll
    for (int p = 0; p < 3; ++p) {
        float x = us[p] * (float)(RES - 1);
        float y = vs[p] * (float)(RES - 1);
        x = fminf(fmaxf(x, 0.0f), (float)(RES - 1));
        y = fminf(fmaxf(y, 0.0f), (float)(RES - 1));
        int x0 = (int)x;
        int y0 = (int)y;
        int x1 = min(x0 + 1, RES - 1);
        int y1 = min(y0 + 1, RES - 1);
        float wx = x - (float)x0;
        float wy = y - (float)y0;
        _Float16 hw00 = (_Float16)((1.0f - wx) * (1.0f - wy));
        _Float16 hw01 = (_Float16)(wx * (1.0f - wy));
        _Float16 hw10 = (_Float16)((1.0f - wx) * wy);
        _Float16 hw11 = (_Float16)(wx * wy);
        h2 h00 = {hw00, hw00}, h01 = {hw01, hw01}, h10 = {hw10, hw10}, h11 = {hw11, hw11};

        const _Float16* base = tp + (size_t)p * NHW * TEXW;
        const _Float16* t00 = base + (size_t)(y0 * RES + x0) * TEXW;
        const _Float16* t01 = base + (size_t)(y0 * RES + x1) * TEXW;
        const _Float16* t10 = base + (size_t)(y1 * RES + x0) * TEXW;
        const _Float16* t11 = base + (size_t)(y1 * RES + x1) * TEXW;

        union TexA { uint4 v; h2 h[4]; } a00, a01, a10, a11;
        union TexB { uint2 v; h2 h[2]; } b00, b01, b10, b11;
        a00.v = *(const uint4*)(t00);  b00.v = *(const uint2*)(t00 + 8);
        a01.v = *(const uint4*)(t01);  b01.v = *(const uint2*)(t01 + 8);
        a10.v = *(const uint4*)(t10);  b10.v = *(const uint2*)(t10 + 8);
        a11.v = *(const uint4*)(t11);  b11.v = *(const uint2*)(t11 + 8);

#pragma unroll
        for (int q = 0; q < 4; ++q)
            f2[p * 6 + q] = a00.h[q] * h00 + a01.h[q] * h01 + a10.h[q] * h10 + a11.h[q] * h11;
#pragma unroll
        for (int q = 0; q < 2; ++q)
            f2[p * 6 + 4 + q] = b00.h[q] * h00 + b01.h[q] * h01 + b10.h[q] * h10 + b11.h[q] * h11;
    }

    float acc[ODIM];
#pragma unroll
    for (int o = 0; o < ODIM; ++o) {
        float sum = 0.0f;
#pragma unroll
        for (int k = 0; k < NF / 2; ++k) {
            union { unsigned u; h2 h; } cv;
            cv.u = w2u[o * (NF / 2) + k];
            sum = fdot2(f2[k], cv.h, sum);
        }
        acc[o] = sum;
    }

    float* op = out + (size_t)idx * ODIM;
#pragma unroll
    for (int q = 0; q < 8; ++q) {
        f32x4 v = {acc[4 * q + 0], acc[4 * q + 1], acc[4 * q + 2], acc[4 * q + 3]};
        *(f32x4*)(op + 4 * q) = v;
    }
}

// ---------------------------------------------------------------------------
// Fallbacks (f32 weights)
// ---------------------------------------------------------------------------
__device__ __forceinline__ void decode_texel(const _Float16* __restrict__ tex, float* __restrict__ o) {
    union { uint4 v; _Float16 h[8]; } A;
    union { uint2 v; _Float16 h[4]; } B;
    A.v = *(const uint4*)(tex);
    B.v = *(const uint2*)(tex + 8);
#pragma unroll
    for (int r = 0; r < 8; ++r) o[r] = (float)A.h[r];
#pragma unroll
    for (int r = 0; r < 4; ++r) o[8 + r] = (float)B.h[r];
}

__device__ __forceinline__ void vme_compute_point(float px, float py, float pz,
                                                  const _Float16* __restrict__ tp,
                                                  const float* __restrict__ w,
                                                  float* __restrict__ op) {
    float f[NF];
    float us[3] = {px, px, py};
    float vs[3] = {py, pz, pz};
#pragma unroll
    for (int p = 0; p < 3; ++p) {
        float x = us[p] * (float)(RES - 1);
        float y = vs[p] * (float)(RES - 1);
        x = fminf(fmaxf(x, 0.0f), (float)(RES - 1));
        y = fminf(fmaxf(y, 0.0f), (float)(RES - 1));
        int x0 = (int)x, y0 = (int)y;
        int x1 = min(x0 + 1, RES - 1), y1 = min(y0 + 1, RES - 1);
        float wx = x - (float)x0, wy = y - (float)y0;
        float w00 = (1.0f - wx) * (1.0f - wy), w01 = wx * (1.0f - wy);
        float w10 = (1.0f - wx) * wy, w11 = wx * wy;
        const _Float16* base = tp + (size_t)p * NHW * TEXW;
        float d00[RANK], d01[RANK], d10[RANK], d11[RANK];
        decode_texel(base + (size_t)(y0 * RES + x0) * TEXW, d00);
        decode_texel(base + (size_t)(y0 * RES + x1) * TEXW, d01);
        decode_texel(base + (size_t)(y1 * RES + x0) * TEXW, d10);
        decode_texel(base + (size_t)(y1 * RES + x1) * TEXW, d11);
#pragma unroll
        for (int r = 0; r < RANK; ++r)
            f[p * RANK + r] = w00 * d00[r] + w01 * d01[r] + w10 * d10[r] + w11 * d11[r];
    }
    float acc[ODIM];
#pragma unroll
    for (int o = 0; o < ODIM; ++o) {
        float s = 0.0f;
#pragma unroll
        for (int k = 0; k < NF; ++k) s += f[k] * w[o * NF + k];
        acc[o] = s;
    }
#pragma unroll
    for (int q = 0; q < 8; ++q) {
        f32x4 v = {acc[4 * q + 0], acc[4 * q + 1], acc[4 * q + 2], acc[4 * q + 3]};
        *(f32x4*)(op + 4 * q) = v;
    }
}

__global__ __launch_bounds__(256) void vme_main(const float* __restrict__ xyz,
                                                const _Float16* __restrict__ tp,
                                                const float* __restrict__ w,
                                                float* __restrict__ out, int n) {
    int i = blockIdx.x * 256 + threadIdx.x;
    if (i >= n) return;
    vme_compute_point(xyz[3 * (size_t)i], xyz[3 * (size_t)i + 1], xyz[3 * (size_t)i + 2],
                      tp, w, out + (size_t)i * ODIM);
}

__global__ __launch_bounds__(256) void vme_main_fb(const float* __restrict__ xyz,
                                                   const float* __restrict__ pa,
                                                   const float* __restrict__ pb,
                                                   const float* __restrict__ pc,
                                                   const float* __restrict__ w,
                                                   float* __restrict__ out, int n) {
    int i = blockIdx.x * 256 + threadIdx.x;
    if (i >= n) return;
    float px = xyz[3 * (size_t)i + 0];
    float py = xyz[3 * (size_t)i + 1];
    float pz = xyz[3 * (size_t)i + 2];
    float f[NF];
    float us[3] = {px, px, py};
    float vs[3] = {py, pz, pz};
#pragma unroll
    for (int p = 0; p < 3; ++p) {
        float x = us[p] * (float)(RES - 1);
        float y = vs[p] * (float)(RES - 1);
        x = fminf(fmaxf(x, 0.0f), (float)(RES - 1));
        y = fminf(fmaxf(y, 0.0f), (float)(RES - 1));
        int x0 = (int)x, y0 = (int)y;
        int x1 = min(x0 + 1, RES - 1), y1 = min(y0 + 1, RES - 1);
        float wx = x - (float)x0, wy = y - (float)y0;
        float w00 = (1.0f - wx) * (1.0f - wy), w01 = wx * (1.0f - wy);
        float w10 = (1.0f - wx) * wy, w11 = wx * wy;
        const float* base = (p == 0) ? pa : (p == 1) ? pb : pc;
        int i00 = y0 * RES + x0, i01 = y0 * RES + x1;
        int i10 = y1 * RES + x0, i11 = y1 * RES + x1;
#pragma unroll
        for (int r = 0; r < RANK; ++r) {
            const float* pr = base + (size_t)r * NHW;
            f[p * RANK + r] = w00 * pr[i00] + w01 * pr[i01] + w10 * pr[i10] + w11 * pr[i11];
        }
    }
    float acc[ODIM];
#pragma unroll
    for (int o = 0; o < ODIM; ++o) {
        float s = 0.0f;
#pragma unroll
        for (int k = 0; k < NF; ++k) s += f[k] * w[o * NF + k];
        acc[o] = s;
    }
    float4* op = (float4*)(out + (size_t)i * ODIM);
#pragma unroll
    for (int q = 0; q < 8; ++q)
        op[q] = make_float4(acc[4 * q], acc[4 * q + 1], acc[4 * q + 2], acc[4 * q + 3]);
}

extern "C" void kernel_launch(void* const* d_in, const int* in_sizes, int n_in,
                              void* d_out, int out_size, void* d_ws, size_t ws_size,
                              hipStream_t stream) {
    const float* xyz = (const float*)d_in[0];
    const float* xy  = (const float*)d_in[1];
    const float* xz  = (const float*)d_in[2];
    const float* yz  = (const float*)d_in[3];
    const float* wml = (const float*)d_in[4];
    float* out = (float*)d_out;

    int n = in_sizes[0] / 3;
    int nblk = (n + 255) / 256;
    int tblk = (3 * NHW + 255) / 256;

    const size_t TPB      = (size_t)3 * NHW * TEXW * sizeof(_Float16);  // 3,538,944
    const size_t OFF_W2   = TPB;
    const size_t OFF_HIST = TPB + 4096;
    const size_t OFF_T    = OFF_HIST + (size_t)NB * SORTB * 4;          // 4 MB matrix
    const size_t OFF_SORT = OFF_T + (size_t)NB * 4;
    const size_t WS_SORTED = OFF_SORT + (size_t)n * 16;

    char* ws = (char*)d_ws;

    if (d_ws && ws_size >= WS_SORTED) {
        _Float16* tp   = (_Float16*)(ws);
        unsigned* w2u  = (unsigned*)(ws + OFF_W2);
        int*      m    = (int*)(ws + OFF_HIST);
        int*      T    = (int*)(ws + OFF_T);
        f32x4*    srt  = (f32x4*)(ws + OFF_SORT);

        vme_transpose<<<tblk, 256, 0, stream>>>(xy, xz, yz, wml, tp, w2u);
        vme_hist<<<SORTB, SORTT, 0, stream>>>(xyz, m, n);
        vme_scan_cols<<<NB / 256, 256, 0, stream>>>(m, T);
        vme_scan_bins<<<1, 1024, 0, stream>>>(T);
        vme_scatter<<<SORTB, SORTT, 0, stream>>>(xyz, m, T, srt, n);
        vme_main_sorted<<<nblk, 256, 0, stream>>>(srt, tp, w2u, out, n);
    } else if (d_ws && ws_size >= TPB) {
        _Float16* tp = (_Float16*)ws;
        vme_transpose<<<tblk, 256, 0, stream>>>(xy, xz, yz, wml, tp, (unsigned*)nullptr);
        vme_main<<<nblk, 256, 0, stream>>>(xyz, tp, wml, out, n);
    } else {
        vme_main_fb<<<nblk, 256, 0, stream>>>(xyz, xy, xz, yz, wml, out, n);
    }
}

// Round 12
// 137.096 us; speedup vs baseline: 2.4444x; 1.3626x over previous
//
#include <hip/hip_runtime.h>
#include <hip/hip_fp16.h>

#define RANK 12
#define RES 192
#define NHW (RES * RES)
#define NF 36
#define ODIM 32
#define TEXW 16            // halfs per texel (12 used + 4 pad) -> 32 B
#define NB 4096            // 16^3 cells
#define SORTB 256          // sort blocks
#define SORTT 1024         // threads per sort block
#define TRB 108            // transpose blocks inside fused pre-kernel (108*1024 >= 110592)
#define LROW 36            // padded row stride (floats): 144 B, 16-B aligned

typedef float f32x4 __attribute__((ext_vector_type(4)));
typedef _Float16 h2 __attribute__((ext_vector_type(2)));

__device__ __forceinline__ float fdot2(h2 a, h2 b, float c) {
#if __has_builtin(__builtin_amdgcn_fdot2)
    return __builtin_amdgcn_fdot2(a, b, c, false);
#else
    return c + (float)a.x * (float)b.x + (float)a.y * (float)b.y;
#endif
}

__device__ __forceinline__ int cell16(float x, float y, float z) {
    int qx = min(15, max(0, (int)(x * 16.0f)));
    int qy = min(15, max(0, (int)(y * 16.0f)));
    int qz = min(15, max(0, (int)(z * 16.0f)));
    return (qz << 8) | (qy << 4) | qx;   // x contiguous -> plane rows contiguous
}

// ---------------------------------------------------------------------------
// Fused pre-pass: blocks [0,TRB) transpose planes -> fp16 texels + pack w;
// blocks [TRB, TRB+SORTB) compute the per-block histogram.
// ---------------------------------------------------------------------------
__global__ __launch_bounds__(SORTT) void vme_pre(const float* __restrict__ a,
                                                 const float* __restrict__ b,
                                                 const float* __restrict__ c,
                                                 const float* __restrict__ w,
                                                 _Float16* __restrict__ t,
                                                 unsigned* __restrict__ w2u,
                                                 const float* __restrict__ xyz,
                                                 int* __restrict__ m, int n) {
    if (blockIdx.x < TRB) {
        int idx = blockIdx.x * SORTT + threadIdx.x;
        if (idx < ODIM * NF / 2) {
            int o = idx / (NF / 2), k = idx - o * (NF / 2);
            union { h2 h; unsigned u; } cv;
            cv.h.x = (_Float16)w[o * NF + 2 * k];
            cv.h.y = (_Float16)w[o * NF + 2 * k + 1];
            w2u[idx] = cv.u;
        }
        if (idx >= 3 * NHW) return;
        int p = idx / NHW;
        int yx = idx - p * NHW;
        const float* src = (p == 0) ? a : (p == 1) ? b : c;
        _Float16* dst = t + (size_t)idx * TEXW;
#pragma unroll
        for (int r = 0; r < RANK; ++r) dst[r] = (_Float16)src[(size_t)r * NHW + yx];
#pragma unroll
        for (int r = RANK; r < TEXW; ++r) dst[r] = (_Float16)0.0f;
        return;
    }
    // histogram part
    __shared__ int h[NB];
    int tt = threadIdx.x, bb = blockIdx.x - TRB;
    for (int k = tt; k < NB; k += SORTT) h[k] = 0;
    __syncthreads();
    int P = (n + SORTB - 1) / SORTB;
    int lo = bb * P, hi = min(n, lo + P);
    for (int i = lo + tt; i < hi; i += SORTT) {
        float x = xyz[3 * (size_t)i + 0];
        float y = xyz[3 * (size_t)i + 1];
        float z = xyz[3 * (size_t)i + 2];
        atomicAdd(&h[cell16(x, y, z)], 1);
    }
    __syncthreads();
    for (int k = tt; k < NB; k += SORTT) m[(size_t)bb * NB + k] = h[k];
}

// ---------------------------------------------------------------------------
// S2a: per-bin exclusive scan over blocks (thread-per-bin; coalesced rows).
// ---------------------------------------------------------------------------
__global__ __launch_bounds__(256) void vme_scan_cols(int* __restrict__ m,
                                                     int* __restrict__ T) {
    int k = blockIdx.x * 256 + threadIdx.x;   // grid = NB/256
    int run = 0;
#pragma unroll 8
    for (int b = 0; b < SORTB; ++b) {
        size_t p = (size_t)b * NB + k;
        int v = m[p];
        m[p] = run;
        run += v;
    }
    T[k] = run;
}

// ---------------------------------------------------------------------------
// S2b: exclusive scan of the NB bin totals (one block)
// ---------------------------------------------------------------------------
__global__ __launch_bounds__(1024) void vme_scan_bins(int* __restrict__ T) {
    __shared__ int sh[1024];
    int t = threadIdx.x;
    int base = t * (NB / 1024);
    int l[NB / 1024];
    int s = 0;
#pragma unroll
    for (int k = 0; k < NB / 1024; ++k) { l[k] = T[base + k]; s += l[k]; }
    sh[t] = s;
    __syncthreads();
    for (int off = 1; off < 1024; off <<= 1) {
        int u = sh[t];
        int add = (t >= off) ? sh[t - off] : 0;
        __syncthreads();
        sh[t] = u + add;
        __syncthreads();
    }
    int run = sh[t] - s;
#pragma unroll
    for (int k = 0; k < NB / 1024; ++k) { T[base + k] = run; run += l[k]; }
}

// ---------------------------------------------------------------------------
// S3: scatter via LDS ranks; base = m[b*NB+k] + T[k]. No global atomics.
// ---------------------------------------------------------------------------
__global__ __launch_bounds__(SORTT) void vme_scatter(const float* __restrict__ xyz,
                                                     const int* __restrict__ m,
                                                     const int* __restrict__ T,
                                                     f32x4* __restrict__ sorted, int n) {
    __shared__ int bases[NB];
    __shared__ int ranks[NB];
    int t = threadIdx.x, b = blockIdx.x;
    for (int k = t; k < NB; k += SORTT) {
        bases[k] = m[(size_t)b * NB + k] + T[k];
        ranks[k] = 0;
    }
    __syncthreads();
    int P = (n + SORTB - 1) / SORTB;
    int lo = b * P, hi = min(n, lo + P);
    for (int i = lo + t; i < hi; i += SORTT) {
        float x = xyz[3 * (size_t)i + 0];
        float y = xyz[3 * (size_t)i + 1];
        float z = xyz[3 * (size_t)i + 2];
        int c = cell16(x, y, z);
        int r = atomicAdd(&ranks[c], 1);
        f32x4 v = {x, y, z, __uint_as_float((unsigned)i)};
        sorted[bases[c] + r] = v;
    }
}

// ---------------------------------------------------------------------------
// Main kernel: packed fp16 interp + v_dot2 MLP, then LDS write-transpose so
// each store instruction emits 8 complete 128-B rows (vs 64 partial touches).
// ---------------------------------------------------------------------------
__global__ __launch_bounds__(256) void vme_main_sorted(const f32x4* __restrict__ sorted,
                                                       const _Float16* __restrict__ tp,
                                                       const unsigned* __restrict__ w2u,
                                                       float* __restrict__ out, int n) {
    __shared__ float lrow[256 * LROW];    // 36864 B
    __shared__ unsigned sidx[256];        // 1 KB
    int tid = threadIdx.x;
    int j = blockIdx.x * 256 + tid;
    bool valid = j < n;

    float acc[ODIM];
#pragma unroll
    for (int o = 0; o < ODIM; ++o) acc[o] = 0.0f;
    unsigned idx = 0xFFFFFFFFu;

    if (valid) {
        f32x4 s = sorted[j];
        idx = __float_as_uint(s.w);
        float us[3] = {s.x, s.x, s.y};
        float vs[3] = {s.y, s.z, s.z};

        h2 f2[NF / 2];
#pragma unroll
        for (int p = 0; p < 3; ++p) {
            float x = us[p] * (float)(RES - 1);
            float y = vs[p] * (float)(RES - 1);
            x = fminf(fmaxf(x, 0.0f), (float)(RES - 1));
            y = fminf(fmaxf(y, 0.0f), (float)(RES - 1));
            int x0 = (int)x;
            int y0 = (int)y;
            int x1 = min(x0 + 1, RES - 1);
            int y1 = min(y0 + 1, RES - 1);
            float wx = x - (float)x0;
            float wy = y - (float)y0;
            _Float16 hw00 = (_Float16)((1.0f - wx) * (1.0f - wy));
            _Float16 hw01 = (_Float16)(wx * (1.0f - wy));
            _Float16 hw10 = (_Float16)((1.0f - wx) * wy);
            _Float16 hw11 = (_Float16)(wx * wy);
            h2 h00 = {hw00, hw00}, h01 = {hw01, hw01}, h10 = {hw10, hw10}, h11 = {hw11, hw11};

            const _Float16* base = tp + (size_t)p * NHW * TEXW;
            const _Float16* t00 = base + (size_t)(y0 * RES + x0) * TEXW;
            const _Float16* t01 = base + (size_t)(y0 * RES + x1) * TEXW;
            const _Float16* t10 = base + (size_t)(y1 * RES + x0) * TEXW;
            const _Float16* t11 = base + (size_t)(y1 * RES + x1) * TEXW;

            union TexA { uint4 v; h2 h[4]; } a00, a01, a10, a11;
            union TexB { uint2 v; h2 h[2]; } b00, b01, b10, b11;
            a00.v = *(const uint4*)(t00);  b00.v = *(const uint2*)(t00 + 8);
            a01.v = *(const uint4*)(t01);  b01.v = *(const uint2*)(t01 + 8);
            a10.v = *(const uint4*)(t10);  b10.v = *(const uint2*)(t10 + 8);
            a11.v = *(const uint4*)(t11);  b11.v = *(const uint2*)(t11 + 8);

#pragma unroll
            for (int q = 0; q < 4; ++q)
                f2[p * 6 + q] = a00.h[q] * h00 + a01.h[q] * h01 + a10.h[q] * h10 + a11.h[q] * h11;
#pragma unroll
            for (int q = 0; q < 2; ++q)
                f2[p * 6 + 4 + q] = b00.h[q] * h00 + b01.h[q] * h01 + b10.h[q] * h10 + b11.h[q] * h11;
        }

#pragma unroll
        for (int o = 0; o < ODIM; ++o) {
            float sum = 0.0f;
#pragma unroll
            for (int k = 0; k < NF / 2; ++k) {
                union { unsigned u; h2 h; } cv;
                cv.u = w2u[o * (NF / 2) + k];
                sum = fdot2(f2[k], cv.h, sum);
            }
            acc[o] = sum;
        }
    }

    sidx[tid] = idx;
#pragma unroll
    for (int q = 0; q < 8; ++q) {
        f32x4 v = {acc[4 * q + 0], acc[4 * q + 1], acc[4 * q + 2], acc[4 * q + 3]};
        *(f32x4*)&lrow[tid * LROW + 4 * q] = v;
    }
    __syncthreads();

    // cooperative row writes: lane handles chunk c of rows r0, r0+32, ...
    int c = tid & 7;
    int r0 = tid >> 3;      // 0..31
#pragma unroll
    for (int rr = 0; rr < 8; ++rr) {
        int r = r0 + rr * 32;
        unsigned id = sidx[r];
        if (id != 0xFFFFFFFFu) {
            f32x4 v = *(const f32x4*)&lrow[r * LROW + 4 * c];
            *(f32x4*)(out + (size_t)id * ODIM + 4 * c) = v;
        }
    }
}

// ---------------------------------------------------------------------------
// Fallbacks (f32 weights)
// ---------------------------------------------------------------------------
__global__ __launch_bounds__(256) void vme_transpose_only(const float* __restrict__ a,
                                                          const float* __restrict__ b,
                                                          const float* __restrict__ c,
                                                          _Float16* __restrict__ t) {
    int idx = blockIdx.x * 256 + threadIdx.x;
    if (idx >= 3 * NHW) return;
    int p = idx / NHW;
    int yx = idx - p * NHW;
    const float* src = (p == 0) ? a : (p == 1) ? b : c;
    _Float16* dst = t + (size_t)idx * TEXW;
#pragma unroll
    for (int r = 0; r < RANK; ++r) dst[r] = (_Float16)src[(size_t)r * NHW + yx];
#pragma unroll
    for (int r = RANK; r < TEXW; ++r) dst[r] = (_Float16)0.0f;
}

__device__ __forceinline__ void decode_texel(const _Float16* __restrict__ tex, float* __restrict__ o) {
    union { uint4 v; _Float16 h[8]; } A;
    union { uint2 v; _Float16 h[4]; } B;
    A.v = *(const uint4*)(tex);
    B.v = *(const uint2*)(tex + 8);
#pragma unroll
    for (int r = 0; r < 8; ++r) o[r] = (float)A.h[r];
#pragma unroll
    for (int r = 0; r < 4; ++r) o[8 + r] = (float)B.h[r];
}

__device__ __forceinline__ void vme_compute_point(float px, float py, float pz,
                                                  const _Float16* __restrict__ tp,
                                                  const float* __restrict__ w,
                                                  float* __restrict__ op) {
    float f[NF];
    float us[3] = {px, px, py};
    float vs[3] = {py, pz, pz};
#pragma unroll
    for (int p = 0; p < 3; ++p) {
        float x = us[p] * (float)(RES - 1);
        float y = vs[p] * (float)(RES - 1);
        x = fminf(fmaxf(x, 0.0f), (float)(RES - 1));
        y = fminf(fmaxf(y, 0.0f), (float)(RES - 1));
        int x0 = (int)x, y0 = (int)y;
        int x1 = min(x0 + 1, RES - 1), y1 = min(y0 + 1, RES - 1);
        float wx = x - (float)x0, wy = y - (float)y0;
        float w00 = (1.0f - wx) * (1.0f - wy), w01 = wx * (1.0f - wy);
        float w10 = (1.0f - wx) * wy, w11 = wx * wy;
        const _Float16* base = tp + (size_t)p * NHW * TEXW;
        float d00[RANK], d01[RANK], d10[RANK], d11[RANK];
        decode_texel(base + (size_t)(y0 * RES + x0) * TEXW, d00);
        decode_texel(base + (size_t)(y0 * RES + x1) * TEXW, d01);
        decode_texel(base + (size_t)(y1 * RES + x0) * TEXW, d10);
        decode_texel(base + (size_t)(y1 * RES + x1) * TEXW, d11);
#pragma unroll
        for (int r = 0; r < RANK; ++r)
            f[p * RANK + r] = w00 * d00[r] + w01 * d01[r] + w10 * d10[r] + w11 * d11[r];
    }
    float acc[ODIM];
#pragma unroll
    for (int o = 0; o < ODIM; ++o) {
        float s = 0.0f;
#pragma unroll
        for (int k = 0; k < NF; ++k) s += f[k] * w[o * NF + k];
        acc[o] = s;
    }
#pragma unroll
    for (int q = 0; q < 8; ++q) {
        f32x4 v = {acc[4 * q + 0], acc[4 * q + 1], acc[4 * q + 2], acc[4 * q + 3]};
        *(f32x4*)(op + 4 * q) = v;
    }
}

__global__ __launch_bounds__(256) void vme_main(const float* __restrict__ xyz,
                                                const _Float16* __restrict__ tp,
                                                const float* __restrict__ w,
                                                float* __restrict__ out, int n) {
    int i = blockIdx.x * 256 + threadIdx.x;
    if (i >= n) return;
    vme_compute_point(xyz[3 * (size_t)i], xyz[3 * (size_t)i + 1], xyz[3 * (size_t)i + 2],
                      tp, w, out + (size_t)i * ODIM);
}

__global__ __launch_bounds__(256) void vme_main_fb(const float* __restrict__ xyz,
                                                   const float* __restrict__ pa,
                                                   const float* __restrict__ pb,
                                                   const float* __restrict__ pc,
                                                   const float* __restrict__ w,
                                                   float* __restrict__ out, int n) {
    int i = blockIdx.x * 256 + threadIdx.x;
    if (i >= n) return;
    float px = xyz[3 * (size_t)i + 0];
    float py = xyz[3 * (size_t)i + 1];
    float pz = xyz[3 * (size_t)i + 2];
    float f[NF];
    float us[3] = {px, px, py};
    float vs[3] = {py, pz, pz};
#pragma unroll
    for (int p = 0; p < 3; ++p) {
        float x = us[p] * (float)(RES - 1);
        float y = vs[p] * (float)(RES - 1);
        x = fminf(fmaxf(x, 0.0f), (float)(RES - 1));
        y = fminf(fmaxf(y, 0.0f), (float)(RES - 1));
        int x0 = (int)x, y0 = (int)y;
        int x1 = min(x0 + 1, RES - 1), y1 = min(y0 + 1, RES - 1);
        float wx = x - (float)x0, wy = y - (float)y0;
        float w00 = (1.0f - wx) * (1.0f - wy), w01 = wx * (1.0f - wy);
        float w10 = (1.0f - wx) * wy, w11 = wx * wy;
        const float* base = (p == 0) ? pa : (p == 1) ? pb : pc;
        int i00 = y0 * RES + x0, i01 = y0 * RES + x1;
        int i10 = y1 * RES + x0, i11 = y1 * RES + x1;
#pragma unroll
        for (int r = 0; r < RANK; ++r) {
            const float* pr = base + (size_t)r * NHW;
            f[p * RANK + r] = w00 * pr[i00] + w01 * pr[i01] + w10 * pr[i10] + w11 * pr[i11];
        }
    }
    float acc[ODIM];
#pragma unroll
    for (int o = 0; o < ODIM; ++o) {
        float s = 0.0f;
#pragma unroll
        for (int k = 0; k < NF; ++k) s += f[k] * w[o * NF + k];
        acc[o] = s;
    }
    float4* op = (float4*)(out + (size_t)i * ODIM);
#pragma unroll
    for (int q = 0; q < 8; ++q)
        op[q] = make_float4(acc[4 * q], acc[4 * q + 1], acc[4 * q + 2], acc[4 * q + 3]);
}

extern "C" void kernel_launch(void* const* d_in, const int* in_sizes, int n_in,
                              void* d_out, int out_size, void* d_ws, size_t ws_size,
                              hipStream_t stream) {
    const float* xyz = (const float*)d_in[0];
    const float* xy  = (const float*)d_in[1];
    const float* xz  = (const float*)d_in[2];
    const float* yz  = (const float*)d_in[3];
    const float* wml = (const float*)d_in[4];
    float* out = (float*)d_out;

    int n = in_sizes[0] / 3;
    int nblk = (n + 255) / 256;
    int tblk = (3 * NHW + 255) / 256;

    const size_t TPB      = (size_t)3 * NHW * TEXW * sizeof(_Float16);  // 3,538,944
    const size_t OFF_W2   = TPB;
    const size_t OFF_HIST = TPB + 4096;
    const size_t OFF_T    = OFF_HIST + (size_t)NB * SORTB * 4;          // 4 MB matrix
    const size_t OFF_SORT = OFF_T + (size_t)NB * 4;
    const size_t WS_SORTED = OFF_SORT + (size_t)n * 16;

    char* ws = (char*)d_ws;

    if (d_ws && ws_size >= WS_SORTED) {
        _Float16* tp   = (_Float16*)(ws);
        unsigned* w2u  = (unsigned*)(ws + OFF_W2);
        int*      m    = (int*)(ws + OFF_HIST);
        int*      T    = (int*)(ws + OFF_T);
        f32x4*    srt  = (f32x4*)(ws + OFF_SORT);

        vme_pre<<<TRB + SORTB, SORTT, 0, stream>>>(xy, xz, yz, wml, tp, w2u, xyz, m, n);
        vme_scan_cols<<<NB / 256, 256, 0, stream>>>(m, T);
        vme_scan_bins<<<1, 1024, 0, stream>>>(T);
        vme_scatter<<<SORTB, SORTT, 0, stream>>>(xyz, m, T, srt, n);
        vme_main_sorted<<<nblk, 256, 0, stream>>>(srt, tp, w2u, out, n);
    } else if (d_ws && ws_size >= TPB) {
        _Float16* tp = (_Float16*)ws;
        vme_transpose_only<<<tblk, 256, 0, stream>>>(xy, xz, yz, tp);
        vme_main<<<nblk, 256, 0, stream>>>(xyz, tp, wml, out, n);
    } else {
        vme_main_fb<<<nblk, 256, 0, stream>>>(xyz, xy, xz, yz, wml, out, n);
    }
}

// Round 14
// 131.354 us; speedup vs baseline: 2.5513x; 1.0437x over previous
//
#include <hip/hip_runtime.h>
#include <hip/hip_fp16.h>

#define RANK 12
#define RES 192
#define NHW (RES * RES)
#define NF 36
#define ODIM 32
#define TEXW 16            // halfs per texel (12 used + 4 pad) -> 32 B
#define NB 4096            // 16^3 cells
#define SORTB 256          // sort blocks
#define SORTT 1024         // threads per sort block
#define TRB 108            // transpose blocks inside fused pre-kernel
#define LROW 36            // padded row stride (floats): 144 B, 16-B aligned

typedef float f32x4 __attribute__((ext_vector_type(4)));
typedef _Float16 h2 __attribute__((ext_vector_type(2)));

__device__ __forceinline__ float fdot2(h2 a, h2 b, float c) {
#if __has_builtin(__builtin_amdgcn_fdot2)
    return __builtin_amdgcn_fdot2(a, b, c, false);
#else
    return c + (float)a.x * (float)b.x + (float)a.y * (float)b.y;
#endif
}

__device__ __forceinline__ int cell16(float x, float y, float z) {
    int qx = min(15, max(0, (int)(x * 16.0f)));
    int qy = min(15, max(0, (int)(y * 16.0f)));
    int qz = min(15, max(0, (int)(z * 16.0f)));
    return (qz << 8) | (qy << 4) | qx;   // x contiguous -> plane rows contiguous
}

// ---------------------------------------------------------------------------
// Fused pre-pass: blocks [0,TRB) transpose planes -> fp16 texels + pack w;
// blocks [TRB, TRB+SORTB) compute the per-block histogram.
// ---------------------------------------------------------------------------
__global__ __launch_bounds__(SORTT) void vme_pre(const float* __restrict__ a,
                                                 const float* __restrict__ b,
                                                 const float* __restrict__ c,
                                                 const float* __restrict__ w,
                                                 _Float16* __restrict__ t,
                                                 unsigned* __restrict__ w2u,
                                                 const float* __restrict__ xyz,
                                                 int* __restrict__ m, int n) {
    if (blockIdx.x < TRB) {
        int idx = blockIdx.x * SORTT + threadIdx.x;
        if (idx < ODIM * NF / 2) {
            int o = idx / (NF / 2), k = idx - o * (NF / 2);
            union { h2 h; unsigned u; } cv;
            cv.h.x = (_Float16)w[o * NF + 2 * k];
            cv.h.y = (_Float16)w[o * NF + 2 * k + 1];
            w2u[idx] = cv.u;
        }
        if (idx >= 3 * NHW) return;
        int p = idx / NHW;
        int yx = idx - p * NHW;
        const float* src = (p == 0) ? a : (p == 1) ? b : c;
        _Float16* dst = t + (size_t)idx * TEXW;
#pragma unroll
        for (int r = 0; r < RANK; ++r) dst[r] = (_Float16)src[(size_t)r * NHW + yx];
#pragma unroll
        for (int r = RANK; r < TEXW; ++r) dst[r] = (_Float16)0.0f;
        return;
    }
    // histogram part
    __shared__ int h[NB];
    int tt = threadIdx.x, bb = blockIdx.x - TRB;
    for (int k = tt; k < NB; k += SORTT) h[k] = 0;
    __syncthreads();
    int P = (n + SORTB - 1) / SORTB;
    int lo = bb * P, hi = min(n, lo + P);
    for (int i = lo + tt; i < hi; i += SORTT) {
        float x = xyz[3 * (size_t)i + 0];
        float y = xyz[3 * (size_t)i + 1];
        float z = xyz[3 * (size_t)i + 2];
        atomicAdd(&h[cell16(x, y, z)], 1);
    }
    __syncthreads();
    for (int k = tt; k < NB; k += SORTT) m[(size_t)bb * NB + k] = h[k];
}

// ---------------------------------------------------------------------------
// S2: per-bin exclusive scan over blocks (thread-per-bin; coalesced rows).
// Leaves raw per-bin totals in T (scanned later inside scatter).
// ---------------------------------------------------------------------------
__global__ __launch_bounds__(256) void vme_scan_cols(int* __restrict__ m,
                                                     int* __restrict__ T) {
    int k = blockIdx.x * 256 + threadIdx.x;   // grid = NB/256
    int run = 0;
#pragma unroll 8
    for (int b = 0; b < SORTB; ++b) {
        size_t p = (size_t)b * NB + k;
        int v = m[p];
        m[p] = run;
        run += v;
    }
    T[k] = run;
}

// ---------------------------------------------------------------------------
// S3: scatter. Each block first exclusive-scans the raw bin totals T in LDS
// (redundant per block, but trivial), then bases = m[b][k] + Tscan[k].
// ---------------------------------------------------------------------------
__global__ __launch_bounds__(SORTT) void vme_scatter(const float* __restrict__ xyz,
                                                     const int* __restrict__ m,
                                                     const int* __restrict__ T,
                                                     f32x4* __restrict__ sorted, int n) {
    __shared__ int sT[NB];              // 16 KB scanned totals
    __shared__ int part[SORTT];         // 4 KB
    __shared__ int bases[NB];           // 16 KB
    __shared__ int ranks[NB];           // 16 KB
    int t = threadIdx.x, b = blockIdx.x;

    // block-local exclusive scan of T[0..NB)
    {
        int base = t * (NB / SORTT);    // 4 per thread
        int l[NB / SORTT];
        int s = 0;
#pragma unroll
        for (int k = 0; k < NB / SORTT; ++k) { l[k] = T[base + k]; s += l[k]; }
        part[t] = s;
        __syncthreads();
        for (int off = 1; off < SORTT; off <<= 1) {
            int u = part[t];
            int add = (t >= off) ? part[t - off] : 0;
            __syncthreads();
            part[t] = u + add;
            __syncthreads();
        }
        int run = part[t] - s;          // exclusive
#pragma unroll
        for (int k = 0; k < NB / SORTT; ++k) { sT[base + k] = run; run += l[k]; }
    }
    __syncthreads();

    for (int k = t; k < NB; k += SORTT) {
        bases[k] = m[(size_t)b * NB + k] + sT[k];
        ranks[k] = 0;
    }
    __syncthreads();
    int P = (n + SORTB - 1) / SORTB;
    int lo = b * P, hi = min(n, lo + P);
    for (int i = lo + t; i < hi; i += SORTT) {
        float x = xyz[3 * (size_t)i + 0];
        float y = xyz[3 * (size_t)i + 1];
        float z = xyz[3 * (size_t)i + 2];
        int c = cell16(x, y, z);
        int r = atomicAdd(&ranks[c], 1);
        f32x4 v = {x, y, z, __uint_as_float((unsigned)i)};
        sorted[bases[c] + r] = v;
    }
}

// ---------------------------------------------------------------------------
// Main kernel: packed fp16 interp + v_dot2 MLP, LDS write-transpose, NT row
// stores (full 128-B rows per lane-octet -> granules merge; L2 stays clean
// for tap reads).
// ---------------------------------------------------------------------------
__global__ __launch_bounds__(256) void vme_main_sorted(const f32x4* __restrict__ sorted,
                                                       const _Float16* __restrict__ tp,
                                                       const unsigned* __restrict__ w2u,
                                                       float* __restrict__ out, int n) {
    __shared__ float lrow[256 * LROW];    // 36864 B
    __shared__ unsigned sidx[256];        // 1 KB
    int tid = threadIdx.x;
    int j = blockIdx.x * 256 + tid;
    bool valid = j < n;

    float acc[ODIM];
#pragma unroll
    for (int o = 0; o < ODIM; ++o) acc[o] = 0.0f;
    unsigned idx = 0xFFFFFFFFu;

    if (valid) {
        f32x4 s = sorted[j];
        idx = __float_as_uint(s.w);
        float us[3] = {s.x, s.x, s.y};
        float vs[3] = {s.y, s.z, s.z};

        h2 f2[NF / 2];
#pragma unroll
        for (int p = 0; p < 3; ++p) {
            float x = us[p] * (float)(RES - 1);
            float y = vs[p] * (float)(RES - 1);
            x = fminf(fmaxf(x, 0.0f), (float)(RES - 1));
            y = fminf(fmaxf(y, 0.0f), (float)(RES - 1));
            int x0 = (int)x;
            int y0 = (int)y;
            int x1 = min(x0 + 1, RES - 1);
            int y1 = min(y0 + 1, RES - 1);
            float wx = x - (float)x0;
            float wy = y - (float)y0;
            _Float16 hw00 = (_Float16)((1.0f - wx) * (1.0f - wy));
            _Float16 hw01 = (_Float16)(wx * (1.0f - wy));
            _Float16 hw10 = (_Float16)((1.0f - wx) * wy);
            _Float16 hw11 = (_Float16)(wx * wy);
            h2 h00 = {hw00, hw00}, h01 = {hw01, hw01}, h10 = {hw10, hw10}, h11 = {hw11, hw11};

            const _Float16* base = tp + (size_t)p * NHW * TEXW;
            const _Float16* t00 = base + (size_t)(y0 * RES + x0) * TEXW;
            const _Float16* t01 = base + (size_t)(y0 * RES + x1) * TEXW;
            const _Float16* t10 = base + (size_t)(y1 * RES + x0) * TEXW;
            const _Float16* t11 = base + (size_t)(y1 * RES + x1) * TEXW;

            union TexA { uint4 v; h2 h[4]; } a00, a01, a10, a11;
            union TexB { uint2 v; h2 h[2]; } b00, b01, b10, b11;
            a00.v = *(const uint4*)(t00);  b00.v = *(const uint2*)(t00 + 8);
            a01.v = *(const uint4*)(t01);  b01.v = *(const uint2*)(t01 + 8);
            a10.v = *(const uint4*)(t10);  b10.v = *(const uint2*)(t10 + 8);
            a11.v = *(const uint4*)(t11);  b11.v = *(const uint2*)(t11 + 8);

#pragma unroll
            for (int q = 0; q < 4; ++q)
                f2[p * 6 + q] = a00.h[q] * h00 + a01.h[q] * h01 + a10.h[q] * h10 + a11.h[q] * h11;
#pragma unroll
            for (int q = 0; q < 2; ++q)
                f2[p * 6 + 4 + q] = b00.h[q] * h00 + b01.h[q] * h01 + b10.h[q] * h10 + b11.h[q] * h11;
        }

#pragma unroll
        for (int o = 0; o < ODIM; ++o) {
            float sum = 0.0f;
#pragma unroll
            for (int k = 0; k < NF / 2; ++k) {
                union { unsigned u; h2 h; } cv;
                cv.u = w2u[o * (NF / 2) + k];
                sum = fdot2(f2[k], cv.h, sum);
            }
            acc[o] = sum;
        }
    }

    sidx[tid] = idx;
#pragma unroll
    for (int q = 0; q < 8; ++q) {
        f32x4 v = {acc[4 * q + 0], acc[4 * q + 1], acc[4 * q + 2], acc[4 * q + 3]};
        *(f32x4*)&lrow[tid * LROW + 4 * q] = v;
    }
    __syncthreads();

    // cooperative row writes: lane handles chunk c of rows r0, r0+32, ...
    int c = tid & 7;
    int r0 = tid >> 3;      // 0..31
#pragma unroll
    for (int rr = 0; rr < 8; ++rr) {
        int r = r0 + rr * 32;
        unsigned id = sidx[r];
        if (id != 0xFFFFFFFFu) {
            f32x4 v = *(const f32x4*)&lrow[r * LROW + 4 * c];
            __builtin_nontemporal_store(v, (f32x4*)(out + (size_t)id * ODIM + 4 * c));
        }
    }
}

// ---------------------------------------------------------------------------
// Fallbacks (f32 weights)
// ---------------------------------------------------------------------------
__global__ __launch_bounds__(256) void vme_transpose_only(const float* __restrict__ a,
                                                          const float* __restrict__ b,
                                                          const float* __restrict__ c,
                                                          _Float16* __restrict__ t) {
    int idx = blockIdx.x * 256 + threadIdx.x;
    if (idx >= 3 * NHW) return;
    int p = idx / NHW;
    int yx = idx - p * NHW;
    const float* src = (p == 0) ? a : (p == 1) ? b : c;
    _Float16* dst = t + (size_t)idx * TEXW;
#pragma unroll
    for (int r = 0; r < RANK; ++r) dst[r] = (_Float16)src[(size_t)r * NHW + yx];
#pragma unroll
    for (int r = RANK; r < TEXW; ++r) dst[r] = (_Float16)0.0f;
}

__device__ __forceinline__ void decode_texel(const _Float16* __restrict__ tex, float* __restrict__ o) {
    union { uint4 v; _Float16 h[8]; } A;
    union { uint2 v; _Float16 h[4]; } B;
    A.v = *(const uint4*)(tex);
    B.v = *(const uint2*)(tex + 8);
#pragma unroll
    for (int r = 0; r < 8; ++r) o[r] = (float)A.h[r];
#pragma unroll
    for (int r = 0; r < 4; ++r) o[8 + r] = (float)B.h[r];
}

__device__ __forceinline__ void vme_compute_point(float px, float py, float pz,
                                                  const _Float16* __restrict__ tp,
                                                  const float* __restrict__ w,
                                                  float* __restrict__ op) {
    float f[NF];
    float us[3] = {px, px, py};
    float vs[3] = {py, pz, pz};
#pragma unroll
    for (int p = 0; p < 3; ++p) {
        float x = us[p] * (float)(RES - 1);
        float y = vs[p] * (float)(RES - 1);
        x = fminf(fmaxf(x, 0.0f), (float)(RES - 1));
        y = fminf(fmaxf(y, 0.0f), (float)(RES - 1));
        int x0 = (int)x, y0 = (int)y;
        int x1 = min(x0 + 1, RES - 1), y1 = min(y0 + 1, RES - 1);
        float wx = x - (float)x0, wy = y - (float)y0;
        float w00 = (1.0f - wx) * (1.0f - wy), w01 = wx * (1.0f - wy);
        float w10 = (1.0f - wx) * wy, w11 = wx * wy;
        const _Float16* base = tp + (size_t)p * NHW * TEXW;
        float d00[RANK], d01[RANK], d10[RANK], d11[RANK];
        decode_texel(base + (size_t)(y0 * RES + x0) * TEXW, d00);
        decode_texel(base + (size_t)(y0 * RES + x1) * TEXW, d01);
        decode_texel(base + (size_t)(y1 * RES + x0) * TEXW, d10);
        decode_texel(base + (size_t)(y1 * RES + x1) * TEXW, d11);
#pragma unroll
        for (int r = 0; r < RANK; ++r)
            f[p * RANK + r] = w00 * d00[r] + w01 * d01[r] + w10 * d10[r] + w11 * d11[r];
    }
    float acc[ODIM];
#pragma unroll
    for (int o = 0; o < ODIM; ++o) {
        float s = 0.0f;
#pragma unroll
        for (int k = 0; k < NF; ++k) s += f[k] * w[o * NF + k];
        acc[o] = s;
    }
#pragma unroll
    for (int q = 0; q < 8; ++q) {
        f32x4 v = {acc[4 * q + 0], acc[4 * q + 1], acc[4 * q + 2], acc[4 * q + 3]};
        *(f32x4*)(op + 4 * q) = v;
    }
}

__global__ __launch_bounds__(256) void vme_main(const float* __restrict__ xyz,
                                                const _Float16* __restrict__ tp,
                                                const float* __restrict__ w,
                                                float* __restrict__ out, int n) {
    int i = blockIdx.x * 256 + threadIdx.x;
    if (i >= n) return;
    vme_compute_point(xyz[3 * (size_t)i], xyz[3 * (size_t)i + 1], xyz[3 * (size_t)i + 2],
                      tp, w, out + (size_t)i * ODIM);
}

__global__ __launch_bounds__(256) void vme_main_fb(const float* __restrict__ xyz,
                                                   const float* __restrict__ pa,
                                                   const float* __restrict__ pb,
                                                   const float* __restrict__ pc,
                                                   const float* __restrict__ w,
                                                   float* __restrict__ out, int n) {
    int i = blockIdx.x * 256 + threadIdx.x;
    if (i >= n) return;
    float px = xyz[3 * (size_t)i + 0];
    float py = xyz[3 * (size_t)i + 1];
    float pz = xyz[3 * (size_t)i + 2];
    float f[NF];
    float us[3] = {px, px, py};
    float vs[3] = {py, pz, pz};
#pragma unroll
    for (int p = 0; p < 3; ++p) {
        float x = us[p] * (float)(RES - 1);
        float y = vs[p] * (float)(RES - 1);
        x = fminf(fmaxf(x, 0.0f), (float)(RES - 1));
        y = fminf(fmaxf(y, 0.0f), (float)(RES - 1));
        int x0 = (int)x, y0 = (int)y;
        int x1 = min(x0 + 1, RES - 1), y1 = min(y0 + 1, RES - 1);
        float wx = x - (float)x0, wy = y - (float)y0;
        float w00 = (1.0f - wx) * (1.0f - wy), w01 = wx * (1.0f - wy);
        float w10 = (1.0f - wx) * wy, w11 = wx * wy;
        const float* base = (p == 0) ? pa : (p == 1) ? pb : pc;
        int i00 = y0 * RES + x0, i01 = y0 * RES + x1;
        int i10 = y1 * RES + x0, i11 = y1 * RES + x1;
#pragma unroll
        for (int r = 0; r < RANK; ++r) {
            const float* pr = base + (size_t)r * NHW;
            f[p * RANK + r] = w00 * pr[i00] + w01 * pr[i01] + w10 * pr[i10] + w11 * pr[i11];
        }
    }
    float acc[ODIM];
#pragma unroll
    for (int o = 0; o < ODIM; ++o) {
        float s = 0.0f;
#pragma unroll
        for (int k = 0; k < NF; ++k) s += f[k] * w[o * NF + k];
        acc[o] = s;
    }
    float4* op = (float4*)(out + (size_t)i * ODIM);
#pragma unroll
    for (int q = 0; q < 8; ++q)
        op[q] = make_float4(acc[4 * q], acc[4 * q + 1], acc[4 * q + 2], acc[4 * q + 3]);
}

extern "C" void kernel_launch(void* const* d_in, const int* in_sizes, int n_in,
                              void* d_out, int out_size, void* d_ws, size_t ws_size,
                              hipStream_t stream) {
    const float* xyz = (const float*)d_in[0];
    const float* xy  = (const float*)d_in[1];
    const float* xz  = (const float*)d_in[2];
    const float* yz  = (const float*)d_in[3];
    const float* wml = (const float*)d_in[4];
    float* out = (float*)d_out;

    int n = in_sizes[0] / 3;
    int nblk = (n + 255) / 256;
    int tblk = (3 * NHW + 255) / 256;

    const size_t TPB      = (size_t)3 * NHW * TEXW * sizeof(_Float16);  // 3,538,944
    const size_t OFF_W2   = TPB;
    const size_t OFF_HIST = TPB + 4096;
    const size_t OFF_T    = OFF_HIST + (size_t)NB * SORTB * 4;          // 4 MB matrix
    const size_t OFF_SORT = OFF_T + (size_t)NB * 4;
    const size_t WS_SORTED = OFF_SORT + (size_t)n * 16;

    char* ws = (char*)d_ws;

    if (d_ws && ws_size >= WS_SORTED) {
        _Float16* tp   = (_Float16*)(ws);
        unsigned* w2u  = (unsigned*)(ws + OFF_W2);
        int*      m    = (int*)(ws + OFF_HIST);
        int*      T    = (int*)(ws + OFF_T);
        f32x4*    srt  = (f32x4*)(ws + OFF_SORT);

        vme_pre<<<TRB + SORTB, SORTT, 0, stream>>>(xy, xz, yz, wml, tp, w2u, xyz, m, n);
        vme_scan_cols<<<NB / 256, 256, 0, stream>>>(m, T);
        vme_scatter<<<SORTB, SORTT, 0, stream>>>(xyz, m, T, srt, n);
        vme_main_sorted<<<nblk, 256, 0, stream>>>(srt, tp, w2u, out, n);
    } else if (d_ws && ws_size >= TPB) {
        _Float16* tp = (_Float16*)ws;
        vme_transpose_only<<<tblk, 256, 0, stream>>>(xy, xz, yz, tp);
        vme_main<<<nblk, 256, 0, stream>>>(xyz, tp, wml, out, n);
    } else {
        vme_main_fb<<<nblk, 256, 0, stream>>>(xyz, xy, xz, yz, wml, out, n);
    }
}